// Round 4
// baseline (523.786 us; speedup 1.0000x reference)
//
#include <hip/hip_runtime.h>
#include <hip/hip_bf16.h>

typedef __hip_bfloat16 bf16;
typedef __attribute__((ext_vector_type(4))) float f32x4;
typedef __attribute__((ext_vector_type(8))) short bf16x8;
typedef __attribute__((ext_vector_type(4))) short s16x4;

#define BB 16
#define HH 128
#define WW 128
#define HWSZ (HH*WW)
// xT: [16][136][136][64] bf16, pad 4
#define XH 136
#define XW 136
#define XPAD 4
// catT: [16][130][130][192] bf16, pad 1
#define CHH 130
#define CWD 130
#define CPAD 1
#define CATC 192

// involutive LDS swizzle: spreads 128B-strided rows across bank quads.
__device__ __forceinline__ int swz(int a) { return a ^ (((a >> 7) & 3) << 4); }

// ---------------- zero only the pad borders of a channel-fast tensor ----------------
__global__ void zero_border(bf16* __restrict__ base, int HP, int WP, int PAD,
                            int Cdim, int slots)
{
    int cg8 = Cdim >> 3;
    int per_b = slots * cg8;
    int idx = blockIdx.x * 256 + threadIdx.x;
    if (idx >= BB * per_b) return;
    int b = idx / per_b;
    int rem = idx - b * per_b;
    int slot = rem / cg8;
    int cg = rem - slot * cg8;
    int top = PAD * WP;
    int h, w;
    if (slot < top)            { h = slot / WP;            w = slot % WP; }
    else if (slot < 2 * top)   { int s = slot - top;       h = HP - PAD + s / WP; w = s % WP; }
    else {
        int s = slot - 2 * top;
        int row = s / (2 * PAD), t = s - row * (2 * PAD);
        h = PAD + row;
        w = (t < PAD) ? t : (WP - 2 * PAD + t);
    }
    bf16x8 z = {0,0,0,0,0,0,0,0};
    *(bf16x8*)(base + (((size_t)b * HP + h) * WP + w) * Cdim + cg * 8) = z;
}

// ---------------- transpose + pad x -> bf16 channel-fast, fused pooling ----------------
__global__ void transpose_pad_pool_x(const float* __restrict__ x, bf16* __restrict__ xT,
                                     float* __restrict__ pooledx)
{
    int h = blockIdx.x, b = blockIdx.y;
    int w  = threadIdx.x & 127;
    int ch = (threadIdx.x >> 7) * 32;
    const float* xb = x + (((size_t)b * 64) * HH + h) * WW + w;
    bf16* dst = xT + (((size_t)b * XH + (h + XPAD)) * XW + (w + XPAD)) * 64;
    float sums[32];
    #pragma unroll
    for (int cg = 0; cg < 4; ++cg) {
        int c0 = ch + cg * 8;
        bf16x8 v;
        #pragma unroll
        for (int j = 0; j < 8; ++j) {
            float f = xb[(size_t)(c0 + j) * HWSZ];
            sums[cg * 8 + j] = f;
            v[j] = __builtin_bit_cast(short, __float2bfloat16(f));
        }
        *(bf16x8*)(dst + c0) = v;
    }
    #pragma unroll
    for (int o = 32; o >= 1; o >>= 1)
        #pragma unroll
        for (int s = 0; s < 32; ++s) sums[s] += __shfl_down(sums[s], o, 64);
    if ((threadIdx.x & 63) == 0) {
        #pragma unroll
        for (int s = 0; s < 32; ++s) atomicAdd(pooledx + b * 64 + ch + s, sums[s]);
    }
}

// ---------------- attention MLP body ----------------
__device__ __forceinline__ void attn_body(int b, const float* pooled, int Cin,
                                          const float* fc1, int hid,
                                          const float* fc2w, const float* fc2b,
                                          float* att, float* sp, float* sh, float* slg)
{
    for (int c = threadIdx.x; c < Cin; c += 64) sp[c] = pooled[b * Cin + c];
    __syncthreads();
    int j = threadIdx.x;
    if (j < hid) {
        float s = 0.f;
        const float4* f4 = (const float4*)(fc1 + (size_t)j * Cin);
        for (int c4 = 0; c4 < Cin / 4; ++c4) {
            float4 v = f4[c4];
            s += v.x * sp[c4*4+0] + v.y * sp[c4*4+1] + v.z * sp[c4*4+2] + v.w * sp[c4*4+3];
        }
        sh[j] = s > 0.f ? s * (1.0f / 16384.0f) : 0.f;   // fold 1/HW
    }
    __syncthreads();
    int k = threadIdx.x;
    if (k < 4) {
        float s = fc2b[k];
        for (int jj = 0; jj < hid; ++jj) s += fc2w[k * hid + jj] * sh[jj];
        slg[k] = s * (1.0f / 34.0f);
    }
    __syncthreads();
    if (threadIdx.x == 0) {
        float m = fmaxf(fmaxf(slg[0], slg[1]), fmaxf(slg[2], slg[3]));
        float e0 = expf(slg[0]-m), e1 = expf(slg[1]-m), e2 = expf(slg[2]-m), e3 = expf(slg[3]-m);
        float inv = 1.0f / (e0+e1+e2+e3);
        att[b*4+0] = e0*inv; att[b*4+1] = e1*inv; att[b*4+2] = e2*inv; att[b*4+3] = e3*inv;
    }
}

// fused: 3 branch attentions (Cin=64, hid=17), grid (16, 3)
__global__ void attention3(const float* __restrict__ pooled,
                           const float* f1a, const float* f2a, const float* ba, float* aa,
                           const float* f1b, const float* f2b, const float* bb, float* ab,
                           const float* f1c, const float* f2c, const float* bc, float* ac)
{
    __shared__ float sp[192], sh[64], slg[4];
    int br = blockIdx.y;
    const float* fc1  = br == 0 ? f1a : br == 1 ? f1b : f1c;
    const float* fc2w = br == 0 ? f2a : br == 1 ? f2b : f2c;
    const float* fc2b = br == 0 ? ba  : br == 1 ? bb  : bc;
    float* att        = br == 0 ? aa  : br == 1 ? ab  : ac;
    attn_body(blockIdx.x, pooled, 64, fc1, 17, fc2w, fc2b, att, sp, sh, slg);
}

__global__ void attention_one(const float* __restrict__ pooled, int Cin,
                              const float* __restrict__ fc1, int hid,
                              const float* __restrict__ fc2w,
                              const float* __restrict__ fc2b, float* __restrict__ att)
{
    __shared__ float sp[192], sh[64], slg[4];
    attn_body(blockIdx.x, pooled, Cin, fc1, hid, fc2w, fc2b, att, sp, sh, slg);
}

// ---------------- aggregate weights -> bf16, MFMA A-fragment order ----------------
// out layout: [b][s = chunk*9+tap][m 4][lane 64][j 8] bf16, where
// co = m*16 + (lane&15), ci = chunk*32 + (lane>>4)*8 + j.
template<int CIN>
__global__ void aggw_frag(const float* __restrict__ w, const float* __restrict__ att,
                          bf16* __restrict__ out)
{
    constexpr int C9 = CIN * 9;
    constexpr int NS = (CIN / 32) * 9;
    __shared__ float wl[4 * C9];
    const int co = blockIdx.x, b = blockIdx.y;
    for (int i = threadIdx.x; i < 4 * C9; i += 256) {
        int k = i / C9, rem = i - k * C9;
        wl[i] = w[((size_t)k * 64 + co) * C9 + rem];
    }
    __syncthreads();
    float a0 = att[b*4+0], a1 = att[b*4+1], a2 = att[b*4+2], a3 = att[b*4+3];
    const int m = co >> 4, l15 = co & 15;
    char* ob = (char*)out + (size_t)b * NS * 4096;
    for (int t = threadIdx.x; t < NS * 32; t += 256) {
        int s = t >> 5, rem = t & 31;
        int gg = rem >> 3, j = rem & 7;
        int chunk = s / 9, tap = s - chunk * 9;
        int ci = chunk * 32 + gg * 8 + j;
        float v = a0 * wl[ci*9 + tap] + a1 * wl[C9 + ci*9 + tap]
                + a2 * wl[2*C9 + ci*9 + tap] + a3 * wl[3*C9 + ci*9 + tap];
        *(bf16*)(ob + ((size_t)((s*4 + m) * 64 + (gg*16 + l15))) * 16 + j * 2) = __float2bfloat16(v);
    }
}

// ---------------- MFMA implicit-GEMM dynamic conv, LDS-staged A + x, dbuf + counted vmcnt ----
// grid (2 wtiles, 32 htiles, 16 b), 512 threads (8 waves), 1 block/CU.
template<int DIL, int CIN, bool RESID>
__global__ __launch_bounds__(512, 2)
void conv_mfma(const bf16* __restrict__ inT, int HPd, int WPd, int PAD,
               const bf16* __restrict__ aggwF,
               const float* __restrict__ xres, float* __restrict__ outf,
               bf16* __restrict__ catT, int catbase, float* __restrict__ poolc)
{
    constexpr int NCHUNK = CIN / 32;
    constexpr int ROWB  = 80 * 64;          // 5120 B per staged row
    constexpr int XBUFB = 6 * ROWB;         // 30720
    constexpr int ABUFB = 9 * 4 * 1024;     // 36864
    constexpr int AOFF  = 2 * XBUFB;        // 61440
    constexpr int SCR   = AOFF + 2 * ABUFB; // 135168 scratch (dummy DMA target)
    constexpr int SCO   = SCR + 1024;       // 136192 pool accumulator
    __shared__ __align__(1024) char lds[SCO + 256];
    float* sco = (float*)(lds + SCO);

    const int b  = blockIdx.z;
    const int hb = blockIdx.y;
    const int wt = blockIdx.x;
    const int r  = hb % DIL;
    const int g4 = hb / DIL;

    const int tid   = threadIdx.x;
    const int wv    = tid >> 6;
    const int lane  = tid & 63;
    const int n16   = lane & 15;
    const int g     = lane >> 4;
    const int orow  = wv & 3;
    const int whalf = wv >> 2;

    const char* inB = (const char*)inT;
    const char* awB = (const char*)aggwF + (size_t)b * NCHUNK * ABUFB;

    if (!RESID && tid < 64) sco[tid] = 0.f;
    __syncthreads();

    // stage one chunk: 30 x-segments + 36 A-segments, padded to 9 loads per wave (72 slots)
    auto stage = [&](int buf, int chunk) {
        #pragma unroll
        for (int k = 0; k < 9; ++k) {
            int i = wv * 9 + k;
            if (i < 30) {
                int row = i / 5, seg = i - row * 5;
                int S = row * ROWB + seg * 1024 + lane * 16;   // physical byte in x buffer
                int L = swz(S);                                 // logical element
                int local = L - row * ROWB;
                int wslot = local >> 6;
                int ci2   = local & 63;
                int h_in = (g4 * 4 + row - 1) * DIL + r;
                long long gb = ((long long)(b * HPd + PAD + h_in) * WPd
                                + (PAD + wt * 64 - 8 + wslot)) * (CIN * 2)
                               + chunk * 64 + ci2;
                __builtin_amdgcn_global_load_lds(
                    (const __attribute__((address_space(1))) void*)(inB + gb),
                    (__attribute__((address_space(3))) void*)(lds + buf * XBUFB + row * ROWB + seg * 1024),
                    16, 0, 0);
            } else if (i < 66) {
                int aseg = i - 30;
                __builtin_amdgcn_global_load_lds(
                    (const __attribute__((address_space(1))) void*)(awB + (size_t)chunk * ABUFB + aseg * 1024 + lane * 16),
                    (__attribute__((address_space(3))) void*)(lds + AOFF + buf * ABUFB + aseg * 1024),
                    16, 0, 0);
            } else {
                __builtin_amdgcn_global_load_lds(
                    (const __attribute__((address_space(1))) void*)(inB + lane * 16),
                    (__attribute__((address_space(3))) void*)(lds + SCR),
                    16, 0, 0);
            }
        }
    };

    f32x4 acc[2][4];
    #pragma unroll
    for (int nt = 0; nt < 2; ++nt)
        #pragma unroll
        for (int m = 0; m < 4; ++m) { f32x4 z = {0.f,0.f,0.f,0.f}; acc[nt][m] = z; }

    stage(0, 0);
    for (int chunk = 0; chunk < NCHUNK; ++chunk) {
        const int p = chunk & 1;
        if (chunk + 1 < NCHUNK) {
            stage(p ^ 1, chunk + 1);
            asm volatile("s_waitcnt vmcnt(9)" ::: "memory");   // current buffers landed
        } else {
            asm volatile("s_waitcnt vmcnt(0)" ::: "memory");
        }
        asm volatile("s_barrier" ::: "memory");

        const char* xb = lds + p * XBUFB;
        const char* ab = lds + AOFF + p * ABUFB;
        #pragma unroll 3
        for (int tap = 0; tap < 9; ++tap) {
            const int kh = tap / 3, kw = tap - kh * 3;
            bf16x8 a[4];
            #pragma unroll
            for (int m = 0; m < 4; ++m)
                a[m] = *(const bf16x8*)(ab + (tap * 4 + m) * 1024 + lane * 16);
            #pragma unroll
            for (int nt = 0; nt < 2; ++nt) {
                int wslot = whalf * 32 + nt * 16 + n16 + (kw - 1) * DIL + 8;
                int addr  = (orow + kh) * ROWB + wslot * 64 + g * 16;
                addr = swz(addr);
                bf16x8 bfr = *(const bf16x8*)(xb + addr);
                #pragma unroll
                for (int m = 0; m < 4; ++m)
                    acc[nt][m] = __builtin_amdgcn_mfma_f32_16x16x32_bf16(a[m], bfr, acc[nt][m], 0, 0, 0);
            }
        }
        asm volatile("s_barrier" ::: "memory");
    }

    // ---- epilogue ----
    const int h_out = (g4 * 4 + orow) * DIL + r;
    const int wbase = wt * 64 + whalf * 32;
    if (RESID) {
        #pragma unroll
        for (int nt = 0; nt < 2; ++nt) {
            int w_out = wbase + nt * 16 + n16;
            #pragma unroll
            for (int m = 0; m < 4; ++m) {
                int co = m * 16 + g * 4;
                size_t base = (((size_t)b * 64 + co) * HH + h_out) * WW + w_out;
                #pragma unroll
                for (int q = 0; q < 4; ++q) {
                    size_t idx = base + (size_t)q * HH * WW;
                    outf[idx] = xres[idx] + acc[nt][m][q];
                }
            }
        }
    } else {
        float csum[4][4];
        #pragma unroll
        for (int m = 0; m < 4; ++m)
            #pragma unroll
            for (int q = 0; q < 4; ++q) csum[m][q] = 0.f;
        #pragma unroll
        for (int nt = 0; nt < 2; ++nt) {
            int w_out = wbase + nt * 16 + n16;
            bf16* dst = catT + (((size_t)b * CHH + (CPAD + h_out)) * CWD + (CPAD + w_out)) * CATC + catbase;
            #pragma unroll
            for (int m = 0; m < 4; ++m) {
                s16x4 pk;
                #pragma unroll
                for (int q = 0; q < 4; ++q) {
                    float v = acc[nt][m][q];
                    v = v >= 0.f ? v : 0.1f * v;               // leaky
                    csum[m][q] += v;
                    pk[q] = __builtin_bit_cast(short, __float2bfloat16(v));
                }
                *(s16x4*)((char*)dst + (m * 16 + g * 4) * 2) = pk;
            }
        }
        // reduce csum over the 16 lanes of each g-group, accumulate per-co into LDS
        #pragma unroll
        for (int m = 0; m < 4; ++m)
            #pragma unroll
            for (int q = 0; q < 4; ++q) {
                float v = csum[m][q];
                v += __shfl_xor(v, 1, 64);
                v += __shfl_xor(v, 2, 64);
                v += __shfl_xor(v, 4, 64);
                v += __shfl_xor(v, 8, 64);
                if (n16 == 0) atomicAdd(&sco[m * 16 + g * 4 + q], v);
            }
        __syncthreads();
        if (tid < 64) atomicAdd(poolc + b * CATC + catbase + tid, sco[tid]);
    }
}

// ---------------- launch ----------------
extern "C" void kernel_launch(void* const* d_in, const int* in_sizes, int n_in,
                              void* d_out, int out_size, void* d_ws, size_t ws_size,
                              hipStream_t stream) {
    const float* x      = (const float*)d_in[0];
    const float* w1     = (const float*)d_in[1];
    const float* fc1_1  = (const float*)d_in[2];
    const float* fc2w_1 = (const float*)d_in[3];
    const float* fc2b_1 = (const float*)d_in[4];
    const float* w2     = (const float*)d_in[5];
    const float* fc1_2  = (const float*)d_in[6];
    const float* fc2w_2 = (const float*)d_in[7];
    const float* fc2b_2 = (const float*)d_in[8];
    const float* w3     = (const float*)d_in[9];
    const float* fc1_3  = (const float*)d_in[10];
    const float* fc2w_3 = (const float*)d_in[11];
    const float* fc2b_3 = (const float*)d_in[12];
    const float* wt     = (const float*)d_in[13];
    const float* fc1_t  = (const float*)d_in[14];
    const float* fc2w_t = (const float*)d_in[15];
    const float* fc2b_t = (const float*)d_in[16];
    float* out = (float*)d_out;
    (void)in_sizes; (void)n_in; (void)out_size; (void)ws_size;

    char* ws = (char*)d_ws;
    auto alloc = [&](size_t bytes) { char* p = ws; ws += (bytes + 255) & ~(size_t)255; return p; };

    bf16*  aggF1   = (bf16*)alloc((size_t)BB * 18 * 4096);
    bf16*  aggF2   = (bf16*)alloc((size_t)BB * 18 * 4096);
    bf16*  aggF3   = (bf16*)alloc((size_t)BB * 18 * 4096);
    bf16*  aggFt   = (bf16*)alloc((size_t)BB * 54 * 4096);
    float* pooledx = (float*)alloc(BB * 64 * 4);
    float* pooledc = (float*)alloc(BB * 192 * 4);
    float* att1    = (float*)alloc(BB * 4 * 4);
    float* att2    = (float*)alloc(BB * 4 * 4);
    float* att3    = (float*)alloc(BB * 4 * 4);
    float* attt    = (float*)alloc(BB * 4 * 4);
    alloc(4096);                                             // guard (stage may underrun)
    const size_t XT_BYTES  = (size_t)BB * XH * XW * 64 * 2;
    bf16* xT   = (bf16*)alloc(XT_BYTES);
    alloc(4096);                                             // guard
    const size_t CAT_BYTES = (size_t)BB * CHH * CWD * CATC * 2;
    bf16* catT = (bf16*)alloc(CAT_BYTES);
    alloc(4096);                                             // guard

    hipMemsetAsync(pooledx, 0, BB * 64 * 4, stream);
    hipMemsetAsync(pooledc, 0, BB * 192 * 4, stream);

    // border-only zeroing (interiors are fully overwritten every call)
    {
        int slots_x = 2 * XPAD * XW + (XH - 2 * XPAD) * 2 * XPAD;    // 2112
        int nthr = BB * slots_x * (64 / 8);
        zero_border<<<(nthr + 255) / 256, 256, 0, stream>>>(xT, XH, XW, XPAD, 64, slots_x);
        int slots_c = 2 * CPAD * CWD + (CHH - 2 * CPAD) * 2 * CPAD;  // 516
        nthr = BB * slots_c * (CATC / 8);
        zero_border<<<(nthr + 255) / 256, 256, 0, stream>>>(catT, CHH, CWD, CPAD, CATC, slots_c);
    }

    transpose_pad_pool_x<<<dim3(128, 16), 256, 0, stream>>>(x, xT, pooledx);

    attention3<<<dim3(16, 3), 64, 0, stream>>>(pooledx,
        fc1_1, fc2w_1, fc2b_1, att1,
        fc1_2, fc2w_2, fc2b_2, att2,
        fc1_3, fc2w_3, fc2b_3, att3);

    aggw_frag<64><<<dim3(64, 16), 256, 0, stream>>>(w1, att1, aggF1);
    aggw_frag<64><<<dim3(64, 16), 256, 0, stream>>>(w2, att2, aggF2);
    aggw_frag<64><<<dim3(64, 16), 256, 0, stream>>>(w3, att3, aggF3);

    dim3 cgrid(2, 32, 16);
    conv_mfma<1, 64, false><<<cgrid, 512, 0, stream>>>(xT, XH, XW, XPAD, aggF1, nullptr, nullptr, catT, 0,   pooledc);
    conv_mfma<2, 64, false><<<cgrid, 512, 0, stream>>>(xT, XH, XW, XPAD, aggF2, nullptr, nullptr, catT, 64,  pooledc);
    conv_mfma<4, 64, false><<<cgrid, 512, 0, stream>>>(xT, XH, XW, XPAD, aggF3, nullptr, nullptr, catT, 128, pooledc);

    attention_one<<<16, 64, 0, stream>>>(pooledc, CATC, fc1_t, 49, fc2w_t, fc2b_t, attt);
    aggw_frag<192><<<dim3(64, 16), 256, 0, stream>>>(wt, attt, aggFt);

    conv_mfma<1, 192, true><<<cgrid, 512, 0, stream>>>(catT, CHH, CWD, CPAD, aggFt, x, out, nullptr, 0, nullptr);
}

// Round 5
// 308.980 us; speedup vs baseline: 1.6952x; 1.6952x over previous
//
#include <hip/hip_runtime.h>
#include <hip/hip_bf16.h>

typedef __hip_bfloat16 bf16;
typedef __attribute__((ext_vector_type(4))) float f32x4;
typedef __attribute__((ext_vector_type(8))) short bf16x8;
typedef __attribute__((ext_vector_type(4))) short s16x4;

#define BB 16
#define HH 128
#define WW 128
#define HWSZ (HH*WW)
// xT: [16][136][136][64] bf16, pad 4
#define XH 136
#define XW 136
#define XPAD 4
// catT: [16][130][130][192] bf16, pad 1
#define CHH 130
#define CWD 130
#define CPAD 1
#define CATC 192

// involutive LDS swizzle: spreads 128B-strided rows across bank quads.
__device__ __forceinline__ int swz(int a) { return a ^ (((a >> 7) & 3) << 4); }

// ---------------- zero only the pad borders of a channel-fast tensor ----------------
__global__ void zero_border(bf16* __restrict__ base, int HP, int WP, int PAD,
                            int Cdim, int slots)
{
    int cg8 = Cdim >> 3;
    int per_b = slots * cg8;
    int idx = blockIdx.x * 256 + threadIdx.x;
    if (idx >= BB * per_b) return;
    int b = idx / per_b;
    int rem = idx - b * per_b;
    int slot = rem / cg8;
    int cg = rem - slot * cg8;
    int top = PAD * WP;
    int h, w;
    if (slot < top)            { h = slot / WP;            w = slot % WP; }
    else if (slot < 2 * top)   { int s = slot - top;       h = HP - PAD + s / WP; w = s % WP; }
    else {
        int s = slot - 2 * top;
        int row = s / (2 * PAD), t = s - row * (2 * PAD);
        h = PAD + row;
        w = (t < PAD) ? t : (WP - 2 * PAD + t);
    }
    bf16x8 z = {0,0,0,0,0,0,0,0};
    *(bf16x8*)(base + (((size_t)b * HP + h) * WP + w) * Cdim + cg * 8) = z;
}

// ---------------- LDS-tiled transpose + pad x -> bf16 channel-fast, fused pool ----------------
// block = (h, b): 64c x 128w slab. fp32 tile[128][65] (pad-65 -> conflict-free both phases).
__global__ __launch_bounds__(256)
void transpose_pad_pool_x(const float* __restrict__ x, bf16* __restrict__ xT,
                          float* __restrict__ pooledx)
{
    __shared__ float tile[128 * 65];
    const int h = blockIdx.x, b = blockIdx.y;
    const int t = threadIdx.x;
    const int w  = t & 127;
    const int chalf = t >> 7;            // 0/1

    // phase 1: coalesced fp32 reads, conflict-free LDS writes (bank = (w+c)%32)
    const float* xb = x + (((size_t)b * 64) * HH + h) * WW + w;
    #pragma unroll
    for (int it = 0; it < 32; ++it) {
        int c = it * 2 + chalf;
        tile[w * 65 + c] = xb[(size_t)c * HWSZ];
    }
    __syncthreads();

    // phase 2: fully coalesced channel-fast 16B writes
    bf16* dst = xT + (((size_t)b * XH + (h + XPAD)) * XW + XPAD) * 64;
    #pragma unroll
    for (int it = 0; it < 4; ++it) {
        int v  = t + it * 256;           // 0..1023
        int ww = v >> 3;
        int c0 = (v & 7) * 8;
        const float* src = tile + ww * 65 + c0;
        bf16x8 pk;
        #pragma unroll
        for (int j = 0; j < 8; ++j)
            pk[j] = __builtin_bit_cast(short, __float2bfloat16(src[j]));
        *(bf16x8*)(dst + (size_t)ww * 64 + c0) = pk;
    }

    // fused pooling: 64 threads each own one channel, column-sum over w
    if (t < 64) {
        float s = 0.f;
        #pragma unroll 4
        for (int ww = 0; ww < 128; ++ww) s += tile[ww * 65 + t];
        atomicAdd(pooledx + b * 64 + t, s);
    }
}

// ---------------- attention MLP body ----------------
__device__ __forceinline__ void attn_body(int b, const float* pooled, int Cin,
                                          const float* fc1, int hid,
                                          const float* fc2w, const float* fc2b,
                                          float* att, float* sp, float* sh, float* slg)
{
    for (int c = threadIdx.x; c < Cin; c += 64) sp[c] = pooled[b * Cin + c];
    __syncthreads();
    int j = threadIdx.x;
    if (j < hid) {
        float s = 0.f;
        const float4* f4 = (const float4*)(fc1 + (size_t)j * Cin);
        for (int c4 = 0; c4 < Cin / 4; ++c4) {
            float4 v = f4[c4];
            s += v.x * sp[c4*4+0] + v.y * sp[c4*4+1] + v.z * sp[c4*4+2] + v.w * sp[c4*4+3];
        }
        sh[j] = s > 0.f ? s * (1.0f / 16384.0f) : 0.f;   // fold 1/HW
    }
    __syncthreads();
    int k = threadIdx.x;
    if (k < 4) {
        float s = fc2b[k];
        for (int jj = 0; jj < hid; ++jj) s += fc2w[k * hid + jj] * sh[jj];
        slg[k] = s * (1.0f / 34.0f);
    }
    __syncthreads();
    if (threadIdx.x == 0) {
        float m = fmaxf(fmaxf(slg[0], slg[1]), fmaxf(slg[2], slg[3]));
        float e0 = expf(slg[0]-m), e1 = expf(slg[1]-m), e2 = expf(slg[2]-m), e3 = expf(slg[3]-m);
        float inv = 1.0f / (e0+e1+e2+e3);
        att[b*4+0] = e0*inv; att[b*4+1] = e1*inv; att[b*4+2] = e2*inv; att[b*4+3] = e3*inv;
    }
}

// fused: 3 branch attentions (Cin=64, hid=17), grid (16, 3)
__global__ void attention3(const float* __restrict__ pooled,
                           const float* f1a, const float* f2a, const float* ba, float* aa,
                           const float* f1b, const float* f2b, const float* bb, float* ab,
                           const float* f1c, const float* f2c, const float* bc, float* ac)
{
    __shared__ float sp[192], sh[64], slg[4];
    int br = blockIdx.y;
    const float* fc1  = br == 0 ? f1a : br == 1 ? f1b : f1c;
    const float* fc2w = br == 0 ? f2a : br == 1 ? f2b : f2c;
    const float* fc2b = br == 0 ? ba  : br == 1 ? bb  : bc;
    float* att        = br == 0 ? aa  : br == 1 ? ab  : ac;
    attn_body(blockIdx.x, pooled, 64, fc1, 17, fc2w, fc2b, att, sp, sh, slg);
}

__global__ void attention_one(const float* __restrict__ pooled, int Cin,
                              const float* __restrict__ fc1, int hid,
                              const float* __restrict__ fc2w,
                              const float* __restrict__ fc2b, float* __restrict__ att)
{
    __shared__ float sp[192], sh[64], slg[4];
    attn_body(blockIdx.x, pooled, Cin, fc1, hid, fc2w, fc2b, att, sp, sh, slg);
}

// ---------------- aggregate weights -> bf16, MFMA A-fragment order ----------------
// out layout: [b][s = chunk*9+tap][m 4][lane 64][j 8] bf16, where
// co = m*16 + (lane&15), ci = chunk*32 + (lane>>4)*8 + j.
template<int CIN>
__global__ void aggw_frag(const float* __restrict__ w, const float* __restrict__ att,
                          bf16* __restrict__ out)
{
    constexpr int C9 = CIN * 9;
    constexpr int NS = (CIN / 32) * 9;
    __shared__ float wl[4 * C9];
    const int co = blockIdx.x, b = blockIdx.y;
    for (int i = threadIdx.x; i < 4 * C9; i += 256) {
        int k = i / C9, rem = i - k * C9;
        wl[i] = w[((size_t)k * 64 + co) * C9 + rem];
    }
    __syncthreads();
    float a0 = att[b*4+0], a1 = att[b*4+1], a2 = att[b*4+2], a3 = att[b*4+3];
    const int m = co >> 4, l15 = co & 15;
    char* ob = (char*)out + (size_t)b * NS * 4096;
    for (int t = threadIdx.x; t < NS * 32; t += 256) {
        int s = t >> 5, rem = t & 31;
        int gg = rem >> 3, j = rem & 7;
        int chunk = s / 9, tap = s - chunk * 9;
        int ci = chunk * 32 + gg * 8 + j;
        float v = a0 * wl[ci*9 + tap] + a1 * wl[C9 + ci*9 + tap]
                + a2 * wl[2*C9 + ci*9 + tap] + a3 * wl[3*C9 + ci*9 + tap];
        *(bf16*)(ob + ((size_t)((s*4 + m) * 64 + (gg*16 + l15))) * 16 + j * 2) = __float2bfloat16(v);
    }
}

// ---------------- MFMA implicit-GEMM dynamic conv, LDS-staged A + x, dbuf + counted vmcnt ----
// grid (2 wtiles, 32 htiles, 16 b), 512 threads (8 waves).
template<int DIL, int CIN, bool RESID>
__global__ __launch_bounds__(512, 2)
void conv_mfma(const bf16* __restrict__ inT, int HPd, int WPd, int PAD,
               const bf16* __restrict__ aggwF,
               const float* __restrict__ xres, float* __restrict__ outf,
               bf16* __restrict__ catT, int catbase, float* __restrict__ poolc)
{
    constexpr int NCHUNK = CIN / 32;
    constexpr int ROWB  = 80 * 64;          // 5120 B per staged row
    constexpr int XBUFB = 6 * ROWB;         // 30720
    constexpr int ABUFB = 9 * 4 * 1024;     // 36864
    constexpr int AOFF  = 2 * XBUFB;        // 61440
    constexpr int SCR   = AOFF + 2 * ABUFB; // 135168 scratch (dummy DMA target)
    constexpr int SCO   = SCR + 1024;       // 136192 pool accumulator
    __shared__ __align__(1024) char lds[SCO + 256];
    float* sco = (float*)(lds + SCO);

    const int b  = blockIdx.z;
    const int hb = blockIdx.y;
    const int wt = blockIdx.x;
    const int r  = hb % DIL;
    const int g4 = hb / DIL;

    const int tid   = threadIdx.x;
    const int wv    = tid >> 6;
    const int lane  = tid & 63;
    const int n16   = lane & 15;
    const int g     = lane >> 4;
    const int orow  = wv & 3;
    const int whalf = wv >> 2;

    const char* inB = (const char*)inT;
    const char* awB = (const char*)aggwF + (size_t)b * NCHUNK * ABUFB;

    if (!RESID && tid < 64) sco[tid] = 0.f;
    __syncthreads();

    // stage one chunk: 30 x-segments + 36 A-segments, padded to 9 loads per wave (72 slots)
    auto stage = [&](int buf, int chunk) {
        #pragma unroll
        for (int k = 0; k < 9; ++k) {
            int i = wv * 9 + k;
            if (i < 30) {
                int row = i / 5, seg = i - row * 5;
                int S = row * ROWB + seg * 1024 + lane * 16;   // physical byte in x buffer
                int L = swz(S);                                 // logical element
                int local = L - row * ROWB;
                int wslot = local >> 6;
                int ci2   = local & 63;
                int h_in = (g4 * 4 + row - 1) * DIL + r;
                long long gb = ((long long)(b * HPd + PAD + h_in) * WPd
                                + (PAD + wt * 64 - 8 + wslot)) * (CIN * 2)
                               + chunk * 64 + ci2;
                __builtin_amdgcn_global_load_lds(
                    (const __attribute__((address_space(1))) void*)(inB + gb),
                    (__attribute__((address_space(3))) void*)(lds + buf * XBUFB + row * ROWB + seg * 1024),
                    16, 0, 0);
            } else if (i < 66) {
                int aseg = i - 30;
                __builtin_amdgcn_global_load_lds(
                    (const __attribute__((address_space(1))) void*)(awB + (size_t)chunk * ABUFB + aseg * 1024 + lane * 16),
                    (__attribute__((address_space(3))) void*)(lds + AOFF + buf * ABUFB + aseg * 1024),
                    16, 0, 0);
            } else {
                __builtin_amdgcn_global_load_lds(
                    (const __attribute__((address_space(1))) void*)(inB + lane * 16),
                    (__attribute__((address_space(3))) void*)(lds + SCR),
                    16, 0, 0);
            }
        }
    };

    f32x4 acc[2][4];
    #pragma unroll
    for (int nt = 0; nt < 2; ++nt)
        #pragma unroll
        for (int m = 0; m < 4; ++m) { f32x4 z = {0.f,0.f,0.f,0.f}; acc[nt][m] = z; }

    stage(0, 0);
    for (int chunk = 0; chunk < NCHUNK; ++chunk) {
        const int p = chunk & 1;
        if (chunk + 1 < NCHUNK) {
            stage(p ^ 1, chunk + 1);
            asm volatile("s_waitcnt vmcnt(9)" ::: "memory");   // current buffers landed
        } else {
            asm volatile("s_waitcnt vmcnt(0)" ::: "memory");
        }
        asm volatile("s_barrier" ::: "memory");

        const char* xb = lds + p * XBUFB;
        const char* ab = lds + AOFF + p * ABUFB;
        #pragma unroll 3
        for (int tap = 0; tap < 9; ++tap) {
            const int kh = tap / 3, kw = tap - kh * 3;
            bf16x8 a[4];
            #pragma unroll
            for (int m = 0; m < 4; ++m)
                a[m] = *(const bf16x8*)(ab + (tap * 4 + m) * 1024 + lane * 16);
            #pragma unroll
            for (int nt = 0; nt < 2; ++nt) {
                int wslot = whalf * 32 + nt * 16 + n16 + (kw - 1) * DIL + 8;
                int addr  = (orow + kh) * ROWB + wslot * 64 + g * 16;
                addr = swz(addr);
                bf16x8 bfr = *(const bf16x8*)(xb + addr);
                #pragma unroll
                for (int m = 0; m < 4; ++m)
                    acc[nt][m] = __builtin_amdgcn_mfma_f32_16x16x32_bf16(a[m], bfr, acc[nt][m], 0, 0, 0);
            }
        }
        asm volatile("s_barrier" ::: "memory");
    }

    // ---- epilogue ----
    const int h_out = (g4 * 4 + orow) * DIL + r;
    const int wbase = wt * 64 + whalf * 32;
    if (RESID) {
        #pragma unroll
        for (int nt = 0; nt < 2; ++nt) {
            int w_out = wbase + nt * 16 + n16;
            #pragma unroll
            for (int m = 0; m < 4; ++m) {
                int co = m * 16 + g * 4;
                size_t base = (((size_t)b * 64 + co) * HH + h_out) * WW + w_out;
                #pragma unroll
                for (int q = 0; q < 4; ++q) {
                    size_t idx = base + (size_t)q * HH * WW;
                    outf[idx] = xres[idx] + acc[nt][m][q];
                }
            }
        }
    } else {
        float csum[4][4];
        #pragma unroll
        for (int m = 0; m < 4; ++m)
            #pragma unroll
            for (int q = 0; q < 4; ++q) csum[m][q] = 0.f;
        #pragma unroll
        for (int nt = 0; nt < 2; ++nt) {
            int w_out = wbase + nt * 16 + n16;
            bf16* dst = catT + (((size_t)b * CHH + (CPAD + h_out)) * CWD + (CPAD + w_out)) * CATC + catbase;
            #pragma unroll
            for (int m = 0; m < 4; ++m) {
                s16x4 pk;
                #pragma unroll
                for (int q = 0; q < 4; ++q) {
                    float v = acc[nt][m][q];
                    v = v >= 0.f ? v : 0.1f * v;               // leaky
                    csum[m][q] += v;
                    pk[q] = __builtin_bit_cast(short, __float2bfloat16(v));
                }
                *(s16x4*)((char*)dst + (m * 16 + g * 4) * 2) = pk;
            }
        }
        // reduce csum over the 16 lanes of each g-group, accumulate per-co into LDS
        #pragma unroll
        for (int m = 0; m < 4; ++m)
            #pragma unroll
            for (int q = 0; q < 4; ++q) {
                float v = csum[m][q];
                v += __shfl_xor(v, 1, 64);
                v += __shfl_xor(v, 2, 64);
                v += __shfl_xor(v, 4, 64);
                v += __shfl_xor(v, 8, 64);
                if (n16 == 0) atomicAdd(&sco[m * 16 + g * 4 + q], v);
            }
        __syncthreads();
        if (tid < 64) atomicAdd(poolc + b * CATC + catbase + tid, sco[tid]);
    }
}

// ---------------- launch ----------------
extern "C" void kernel_launch(void* const* d_in, const int* in_sizes, int n_in,
                              void* d_out, int out_size, void* d_ws, size_t ws_size,
                              hipStream_t stream) {
    const float* x      = (const float*)d_in[0];
    const float* w1     = (const float*)d_in[1];
    const float* fc1_1  = (const float*)d_in[2];
    const float* fc2w_1 = (const float*)d_in[3];
    const float* fc2b_1 = (const float*)d_in[4];
    const float* w2     = (const float*)d_in[5];
    const float* fc1_2  = (const float*)d_in[6];
    const float* fc2w_2 = (const float*)d_in[7];
    const float* fc2b_2 = (const float*)d_in[8];
    const float* w3     = (const float*)d_in[9];
    const float* fc1_3  = (const float*)d_in[10];
    const float* fc2w_3 = (const float*)d_in[11];
    const float* fc2b_3 = (const float*)d_in[12];
    const float* wt     = (const float*)d_in[13];
    const float* fc1_t  = (const float*)d_in[14];
    const float* fc2w_t = (const float*)d_in[15];
    const float* fc2b_t = (const float*)d_in[16];
    float* out = (float*)d_out;
    (void)in_sizes; (void)n_in; (void)out_size; (void)ws_size;

    char* ws = (char*)d_ws;
    auto alloc = [&](size_t bytes) { char* p = ws; ws += (bytes + 255) & ~(size_t)255; return p; };

    bf16*  aggF1   = (bf16*)alloc((size_t)BB * 18 * 4096);
    bf16*  aggF2   = (bf16*)alloc((size_t)BB * 18 * 4096);
    bf16*  aggF3   = (bf16*)alloc((size_t)BB * 18 * 4096);
    bf16*  aggFt   = (bf16*)alloc((size_t)BB * 54 * 4096);
    float* pooledx = (float*)alloc(BB * 64 * 4);
    float* pooledc = (float*)alloc(BB * 192 * 4);
    float* att1    = (float*)alloc(BB * 4 * 4);
    float* att2    = (float*)alloc(BB * 4 * 4);
    float* att3    = (float*)alloc(BB * 4 * 4);
    float* attt    = (float*)alloc(BB * 4 * 4);
    alloc(4096);                                             // guard (stage may underrun)
    const size_t XT_BYTES  = (size_t)BB * XH * XW * 64 * 2;
    bf16* xT   = (bf16*)alloc(XT_BYTES);
    alloc(4096);                                             // guard
    const size_t CAT_BYTES = (size_t)BB * CHH * CWD * CATC * 2;
    bf16* catT = (bf16*)alloc(CAT_BYTES);
    alloc(4096);                                             // guard

    hipMemsetAsync(pooledx, 0, BB * 64 * 4, stream);
    hipMemsetAsync(pooledc, 0, BB * 192 * 4, stream);

    // border-only zeroing (interiors are fully overwritten every call)
    {
        int slots_x = 2 * XPAD * XW + (XH - 2 * XPAD) * 2 * XPAD;    // 2112
        int nthr = BB * slots_x * (64 / 8);
        zero_border<<<(nthr + 255) / 256, 256, 0, stream>>>(xT, XH, XW, XPAD, 64, slots_x);
        int slots_c = 2 * CPAD * CWD + (CHH - 2 * CPAD) * 2 * CPAD;  // 516
        nthr = BB * slots_c * (CATC / 8);
        zero_border<<<(nthr + 255) / 256, 256, 0, stream>>>(catT, CHH, CWD, CPAD, CATC, slots_c);
    }

    transpose_pad_pool_x<<<dim3(128, 16), 256, 0, stream>>>(x, xT, pooledx);

    attention3<<<dim3(16, 3), 64, 0, stream>>>(pooledx,
        fc1_1, fc2w_1, fc2b_1, att1,
        fc1_2, fc2w_2, fc2b_2, att2,
        fc1_3, fc2w_3, fc2b_3, att3);

    aggw_frag<64><<<dim3(64, 16), 256, 0, stream>>>(w1, att1, aggF1);
    aggw_frag<64><<<dim3(64, 16), 256, 0, stream>>>(w2, att2, aggF2);
    aggw_frag<64><<<dim3(64, 16), 256, 0, stream>>>(w3, att3, aggF3);

    dim3 cgrid(2, 32, 16);
    conv_mfma<1, 64, false><<<cgrid, 512, 0, stream>>>(xT, XH, XW, XPAD, aggF1, nullptr, nullptr, catT, 0,   pooledc);
    conv_mfma<2, 64, false><<<cgrid, 512, 0, stream>>>(xT, XH, XW, XPAD, aggF2, nullptr, nullptr, catT, 64,  pooledc);
    conv_mfma<4, 64, false><<<cgrid, 512, 0, stream>>>(xT, XH, XW, XPAD, aggF3, nullptr, nullptr, catT, 128, pooledc);

    attention_one<<<16, 64, 0, stream>>>(pooledc, CATC, fc1_t, 49, fc2w_t, fc2b_t, attt);
    aggw_frag<192><<<dim3(64, 16), 256, 0, stream>>>(wt, attt, aggFt);

    conv_mfma<1, 192, true><<<cgrid, 512, 0, stream>>>(catT, CHH, CWD, CPAD, aggFt, x, out, nullptr, 0, nullptr);
}

// Round 6
// 288.805 us; speedup vs baseline: 1.8136x; 1.0699x over previous
//
#include <hip/hip_runtime.h>
#include <hip/hip_bf16.h>

typedef __hip_bfloat16 bf16;
typedef __attribute__((ext_vector_type(4))) float f32x4;
typedef __attribute__((ext_vector_type(8))) short bf16x8;
typedef __attribute__((ext_vector_type(4))) short s16x4;

#define BB 16
#define HH 128
#define WW 128
#define HWSZ (HH*WW)
// xT: [16][136][136][64] bf16, pad 4
#define XH 136
#define XW 136
#define XPAD 4
// catT: [16][130][130][192] bf16, pad 1
#define CHH 130
#define CWD 130
#define CPAD 1
#define CATC 192

// involutive LDS swizzle: spreads 128B-strided rows across bank quads.
__device__ __forceinline__ int swz(int a) { return a ^ (((a >> 7) & 3) << 4); }

// ---------------- zero only the pad borders of a channel-fast tensor ----------------
__global__ void zero_border(bf16* __restrict__ base, int HP, int WP, int PAD,
                            int Cdim, int slots)
{
    int cg8 = Cdim >> 3;
    int per_b = slots * cg8;
    int idx = blockIdx.x * 256 + threadIdx.x;
    if (idx >= BB * per_b) return;
    int b = idx / per_b;
    int rem = idx - b * per_b;
    int slot = rem / cg8;
    int cg = rem - slot * cg8;
    int top = PAD * WP;
    int h, w;
    if (slot < top)            { h = slot / WP;            w = slot % WP; }
    else if (slot < 2 * top)   { int s = slot - top;       h = HP - PAD + s / WP; w = s % WP; }
    else {
        int s = slot - 2 * top;
        int row = s / (2 * PAD), t = s - row * (2 * PAD);
        h = PAD + row;
        w = (t < PAD) ? t : (WP - 2 * PAD + t);
    }
    bf16x8 z = {0,0,0,0,0,0,0,0};
    *(bf16x8*)(base + (((size_t)b * HP + h) * WP + w) * Cdim + cg * 8) = z;
}

// ---------------- LDS-tiled transpose + pad x -> bf16 channel-fast, fused pool ----------------
__global__ __launch_bounds__(256)
void transpose_pad_pool_x(const float* __restrict__ x, bf16* __restrict__ xT,
                          float* __restrict__ pooledx)
{
    __shared__ float tile[128 * 65];
    const int h = blockIdx.x, b = blockIdx.y;
    const int t = threadIdx.x;
    const int w  = t & 127;
    const int chalf = t >> 7;            // 0/1

    const float* xb = x + (((size_t)b * 64) * HH + h) * WW + w;
    #pragma unroll
    for (int it = 0; it < 32; ++it) {
        int c = it * 2 + chalf;
        tile[w * 65 + c] = xb[(size_t)c * HWSZ];
    }
    __syncthreads();

    bf16* dst = xT + (((size_t)b * XH + (h + XPAD)) * XW + XPAD) * 64;
    #pragma unroll
    for (int it = 0; it < 4; ++it) {
        int v  = t + it * 256;           // 0..1023
        int ww = v >> 3;
        int c0 = (v & 7) * 8;
        const float* src = tile + ww * 65 + c0;
        bf16x8 pk;
        #pragma unroll
        for (int j = 0; j < 8; ++j)
            pk[j] = __builtin_bit_cast(short, __float2bfloat16(src[j]));
        *(bf16x8*)(dst + (size_t)ww * 64 + c0) = pk;
    }

    if (t < 64) {
        float s = 0.f;
        #pragma unroll 4
        for (int ww = 0; ww < 128; ++ww) s += tile[ww * 65 + t];
        atomicAdd(pooledx + b * 64 + t, s);
    }
}

// ---------------- attention MLP body ----------------
__device__ __forceinline__ void attn_body(int b, const float* pooled, int Cin,
                                          const float* fc1, int hid,
                                          const float* fc2w, const float* fc2b,
                                          float* att, float* sp, float* sh, float* slg)
{
    for (int c = threadIdx.x; c < Cin; c += 64) sp[c] = pooled[b * Cin + c];
    __syncthreads();
    int j = threadIdx.x;
    if (j < hid) {
        float s = 0.f;
        const float4* f4 = (const float4*)(fc1 + (size_t)j * Cin);
        for (int c4 = 0; c4 < Cin / 4; ++c4) {
            float4 v = f4[c4];
            s += v.x * sp[c4*4+0] + v.y * sp[c4*4+1] + v.z * sp[c4*4+2] + v.w * sp[c4*4+3];
        }
        sh[j] = s > 0.f ? s * (1.0f / 16384.0f) : 0.f;   // fold 1/HW
    }
    __syncthreads();
    int k = threadIdx.x;
    if (k < 4) {
        float s = fc2b[k];
        for (int jj = 0; jj < hid; ++jj) s += fc2w[k * hid + jj] * sh[jj];
        slg[k] = s * (1.0f / 34.0f);
    }
    __syncthreads();
    if (threadIdx.x == 0) {
        float m = fmaxf(fmaxf(slg[0], slg[1]), fmaxf(slg[2], slg[3]));
        float e0 = expf(slg[0]-m), e1 = expf(slg[1]-m), e2 = expf(slg[2]-m), e3 = expf(slg[3]-m);
        float inv = 1.0f / (e0+e1+e2+e3);
        att[b*4+0] = e0*inv; att[b*4+1] = e1*inv; att[b*4+2] = e2*inv; att[b*4+3] = e3*inv;
    }
}

__global__ void attention3(const float* __restrict__ pooled,
                           const float* f1a, const float* f2a, const float* ba, float* aa,
                           const float* f1b, const float* f2b, const float* bb, float* ab,
                           const float* f1c, const float* f2c, const float* bc, float* ac)
{
    __shared__ float sp[192], sh[64], slg[4];
    int br = blockIdx.y;
    const float* fc1  = br == 0 ? f1a : br == 1 ? f1b : f1c;
    const float* fc2w = br == 0 ? f2a : br == 1 ? f2b : f2c;
    const float* fc2b = br == 0 ? ba  : br == 1 ? bb  : bc;
    float* att        = br == 0 ? aa  : br == 1 ? ab  : ac;
    attn_body(blockIdx.x, pooled, 64, fc1, 17, fc2w, fc2b, att, sp, sh, slg);
}

__global__ void attention_one(const float* __restrict__ pooled, int Cin,
                              const float* __restrict__ fc1, int hid,
                              const float* __restrict__ fc2w,
                              const float* __restrict__ fc2b, float* __restrict__ att)
{
    __shared__ float sp[192], sh[64], slg[4];
    attn_body(blockIdx.x, pooled, Cin, fc1, hid, fc2w, fc2b, att, sp, sh, slg);
}

// ---------------- aggregate weights -> bf16, MFMA A-fragment order ----------------
// out layout: [b][s = chunk*9+tap][m 4][lane 64][j 8] bf16, where
// co = m*16 + (lane&15), ci = chunk*32 + (lane>>4)*8 + j.
template<int CIN>
__global__ void aggw_frag(const float* __restrict__ w, const float* __restrict__ att,
                          bf16* __restrict__ out)
{
    constexpr int C9 = CIN * 9;
    constexpr int NS = (CIN / 32) * 9;
    __shared__ float wl[4 * C9];
    const int co = blockIdx.x, b = blockIdx.y;
    for (int i = threadIdx.x; i < 4 * C9; i += 256) {
        int k = i / C9, rem = i - k * C9;
        wl[i] = w[((size_t)k * 64 + co) * C9 + rem];
    }
    __syncthreads();
    float a0 = att[b*4+0], a1 = att[b*4+1], a2 = att[b*4+2], a3 = att[b*4+3];
    const int m = co >> 4, l15 = co & 15;
    char* ob = (char*)out + (size_t)b * NS * 4096;
    for (int t = threadIdx.x; t < NS * 32; t += 256) {
        int s = t >> 5, rem = t & 31;
        int gg = rem >> 3, j = rem & 7;
        int chunk = s / 9, tap = s - chunk * 9;
        int ci = chunk * 32 + gg * 8 + j;
        float v = a0 * wl[ci*9 + tap] + a1 * wl[C9 + ci*9 + tap]
                + a2 * wl[2*C9 + ci*9 + tap] + a3 * wl[3*C9 + ci*9 + tap];
        *(bf16*)(ob + ((size_t)((s*4 + m) * 64 + (gg*16 + l15))) * 16 + j * 2) = __float2bfloat16(v);
    }
}

// ---------------- MFMA implicit-GEMM dynamic conv ----------------
// grid (2 wt, 8 hb, 16 b) = 256 blocks (1/CU), 512 threads (8 waves).
// Block: 64 co x 16 out rows x 64 w. Iter = (chunk, hgroup u in {0,1}) of 8 rows.
// Wave wv = one row of the hgroup, full 64 w (4 n-tiles), 4 m-tiles.
template<int DIL, int CIN, bool RESID>
__global__ __launch_bounds__(512, 2)
void conv_mfma(const bf16* __restrict__ inT, int HPd, int WPd, int PAD,
               const bf16* __restrict__ aggwF,
               const float* __restrict__ xres, float* __restrict__ outf,
               bf16* __restrict__ catT, int catbase, float* __restrict__ poolc)
{
    constexpr int NCHUNK = CIN / 32;
    constexpr int ROWB   = 72 * 64;          // 4608 B per staged row (4+64+4 w-slots)
    constexpr int XBUF   = 10 * ROWB;        // 46080
    constexpr int XB1    = 65536;            // buf1 base (power of 2 -> XOR toggle)
    constexpr int ABASE  = XB1 + XBUF;       // 111616
    constexpr int ABUFB  = 9 * 4 * 1024;     // 36864
    constexpr int SCR    = ABASE + ABUFB;    // 148480 (dummy DMA target)
    constexpr int SCO    = SCR + 1024;       // 149504 pool accumulator
    __shared__ __align__(1024) char lds[SCO + 256];
    float* sco = (float*)(lds + SCO);

    const int b  = blockIdx.z;
    const int hb = blockIdx.y;               // 0..7
    const int wt = blockIdx.x;               // 0..1
    const int r  = hb % DIL;
    const int q  = hb / DIL;

    const int tid  = threadIdx.x;
    const int wv   = tid >> 6;               // wave = row of hgroup
    const int lane = tid & 63;
    const int n16  = lane & 15;
    const int g    = lane >> 4;

    const char* inB = (const char*)inT;
    const char* awB = (const char*)aggwF + (size_t)b * (NCHUNK * ABUFB);

    if (!RESID && tid < 64) sco[tid] = 0.f;
    __syncthreads();

    // precomputed swizzled B-read addrs (buf0, kh=0); kh via +kh*ROWB imm (commutes with swz)
    int baddr[12];
    #pragma unroll
    for (int nt = 0; nt < 4; ++nt)
        #pragma unroll
        for (int kw = 0; kw < 3; ++kw) {
            int a = wv * ROWB + (4 + nt * 16 + n16 + (kw - 1) * DIL) * 64 + g * 16;
            baddr[nt * 3 + kw] = swz(a);
        }

    // X staging source addrs, state t=0 (chunk 0, u=0); 6 loads/wave (45 real + 3 dummy)
    long long gx[6];
    const long long DU = (long long)8 * DIL * WPd * (CIN * 2);
    #pragma unroll
    for (int k = 0; k < 6; ++k) {
        int i = wv * 6 + k;
        int ii = i < 45 ? i : 0;
        int S = ii * 1024 + lane * 16;       // physical byte in buffer
        int L = swz(S);                      // logical byte
        int row = L / ROWB;
        int rem = L - row * ROWB;
        int wslot = rem >> 6;
        int ci2 = rem & 63;
        int h_in = (q * 16 + row - 1) * DIL + r;
        gx[k] = ((long long)(b * HPd + PAD + h_in) * WPd + (PAD + wt * 64 - 4 + wslot)) * (CIN * 2) + ci2;
    }

    auto issueX = [&](int dbase) {
        #pragma unroll
        for (int k = 0; k < 6; ++k) {
            const bool real = (wv * 6 + k) < 45;
            const char* src = real ? (inB + gx[k]) : (inB + (size_t)lane * 16);
            int doff = real ? (dbase + (wv * 6 + k) * 1024) : SCR;
            __builtin_amdgcn_global_load_lds(
                (const __attribute__((address_space(1))) void*)src,
                (__attribute__((address_space(3))) void*)(lds + doff), 16, 0, 0);
        }
    };
    auto issueA = [&](int c) {
        const char* abase = awB + (size_t)c * ABUFB + (size_t)lane * 16;
        #pragma unroll
        for (int k = 0; k < 5; ++k) {
            int i = wv * 5 + k;
            const bool real = i < 36;
            const char* src = real ? (abase + i * 1024) : (inB + (size_t)lane * 16);
            int doff = real ? (ABASE + i * 1024) : SCR;
            __builtin_amdgcn_global_load_lds(
                (const __attribute__((address_space(1))) void*)src,
                (__attribute__((address_space(3))) void*)(lds + doff), 16, 0, 0);
        }
    };

    f32x4 acc0[4][4], acc1[4][4];
    #pragma unroll
    for (int nt = 0; nt < 4; ++nt)
        #pragma unroll
        for (int m = 0; m < 4; ++m) {
            f32x4 z = {0.f,0.f,0.f,0.f};
            acc0[nt][m] = z; acc1[nt][m] = z;
        }

    auto compute = [&](f32x4 (&acc)[4][4]) {
        #pragma unroll
        for (int tap = 0; tap < 9; ++tap) {
            const int kh = tap / 3, kw = tap - kh * 3;
            bf16x8 a[4];
            #pragma unroll
            for (int m = 0; m < 4; ++m)
                a[m] = *(const bf16x8*)(lds + ABASE + (tap * 4 + m) * 1024 + lane * 16);
            #pragma unroll
            for (int nt = 0; nt < 4; ++nt) {
                bf16x8 bb = *(const bf16x8*)(lds + (baddr[nt * 3 + kw] + kh * ROWB));
                #pragma unroll
                for (int m = 0; m < 4; ++m)
                    acc[nt][m] = __builtin_amdgcn_mfma_f32_16x16x32_bf16(a[m], bb, acc[nt][m], 0, 0, 0);
            }
        }
    };

    // ---- prologue: stage A(0) + X(t=0), drain ----
    issueA(0);
    issueX(0);
    #pragma unroll
    for (int k = 0; k < 6; ++k) gx[k] += DU;            // -> state(1)
    asm volatile("s_waitcnt vmcnt(0)" ::: "memory");
    __builtin_amdgcn_s_barrier();

    for (int c = 0; c < NCHUNK; ++c) {
        // ---- iter u=0 (t=2c), buf0 ----
        if (c > 0) {
            __builtin_amdgcn_s_barrier();               // all done with compute(t-1)
            issueA(c);                                  // A(c) before X -> covered by vmcnt(6)
        }
        issueX(XB1);                                    // X(2c+1) -> buf1
        #pragma unroll
        for (int k = 0; k < 6; ++k) gx[k] += -DU + 64;  // -> state(2c+2): next chunk, u=0
        asm volatile("s_waitcnt vmcnt(6)" ::: "memory");
        __builtin_amdgcn_s_barrier();
        compute(acc0);
        #pragma unroll
        for (int j = 0; j < 12; ++j) baddr[j] ^= XB1;   // -> buf1
        // ---- iter u=1 (t=2c+1), buf1 ----
        __builtin_amdgcn_s_barrier();                   // all done with compute(t-1)
        if (c + 1 < NCHUNK) {
            issueX(0);                                  // X(2c+2) -> buf0
            #pragma unroll
            for (int k = 0; k < 6; ++k) gx[k] += DU;    // -> state(2c+3)
            asm volatile("s_waitcnt vmcnt(6)" ::: "memory");
        } else {
            asm volatile("s_waitcnt vmcnt(0)" ::: "memory");
        }
        __builtin_amdgcn_s_barrier();
        compute(acc1);
        #pragma unroll
        for (int j = 0; j < 12; ++j) baddr[j] ^= XB1;   // -> buf0
    }

    // ---- epilogue ----
    float csum[4][4];
    #pragma unroll
    for (int m = 0; m < 4; ++m)
        #pragma unroll
        for (int qq = 0; qq < 4; ++qq) csum[m][qq] = 0.f;

    auto epilogue = [&](f32x4 (&acc)[4][4], int u) {
        const int h_out = ((q * 2 + u) * 8 + wv) * DIL + r;
        if (RESID) {
            #pragma unroll
            for (int nt = 0; nt < 4; ++nt) {
                int w_out = wt * 64 + nt * 16 + n16;
                #pragma unroll
                for (int m = 0; m < 4; ++m) {
                    int co = m * 16 + g * 4;
                    size_t base = (((size_t)b * 64 + co) * HH + h_out) * WW + w_out;
                    #pragma unroll
                    for (int qq = 0; qq < 4; ++qq) {
                        size_t idx = base + (size_t)qq * HWSZ;
                        outf[idx] = xres[idx] + acc[nt][m][qq];
                    }
                }
            }
        } else {
            #pragma unroll
            for (int nt = 0; nt < 4; ++nt) {
                int w_out = wt * 64 + nt * 16 + n16;
                bf16* dst = catT + (((size_t)b * CHH + (CPAD + h_out)) * CWD + (CPAD + w_out)) * CATC + catbase;
                #pragma unroll
                for (int m = 0; m < 4; ++m) {
                    s16x4 pk;
                    #pragma unroll
                    for (int qq = 0; qq < 4; ++qq) {
                        float v = acc[nt][m][qq];
                        v = v >= 0.f ? v : 0.1f * v;        // leaky
                        csum[m][qq] += v;
                        pk[qq] = __builtin_bit_cast(short, __float2bfloat16(v));
                    }
                    *(s16x4*)((char*)dst + (m * 16 + g * 4) * 2) = pk;
                }
            }
        }
    };
    epilogue(acc0, 0);
    epilogue(acc1, 1);

    if (!RESID) {
        #pragma unroll
        for (int m = 0; m < 4; ++m)
            #pragma unroll
            for (int qq = 0; qq < 4; ++qq) {
                float v = csum[m][qq];
                v += __shfl_xor(v, 1, 64);
                v += __shfl_xor(v, 2, 64);
                v += __shfl_xor(v, 4, 64);
                v += __shfl_xor(v, 8, 64);
                if (n16 == 0) atomicAdd(&sco[m * 16 + g * 4 + qq], v);
            }
        __syncthreads();
        if (tid < 64) atomicAdd(poolc + b * CATC + catbase + tid, sco[tid]);
    }
}

// ---------------- launch ----------------
extern "C" void kernel_launch(void* const* d_in, const int* in_sizes, int n_in,
                              void* d_out, int out_size, void* d_ws, size_t ws_size,
                              hipStream_t stream) {
    const float* x      = (const float*)d_in[0];
    const float* w1     = (const float*)d_in[1];
    const float* fc1_1  = (const float*)d_in[2];
    const float* fc2w_1 = (const float*)d_in[3];
    const float* fc2b_1 = (const float*)d_in[4];
    const float* w2     = (const float*)d_in[5];
    const float* fc1_2  = (const float*)d_in[6];
    const float* fc2w_2 = (const float*)d_in[7];
    const float* fc2b_2 = (const float*)d_in[8];
    const float* w3     = (const float*)d_in[9];
    const float* fc1_3  = (const float*)d_in[10];
    const float* fc2w_3 = (const float*)d_in[11];
    const float* fc2b_3 = (const float*)d_in[12];
    const float* wt     = (const float*)d_in[13];
    const float* fc1_t  = (const float*)d_in[14];
    const float* fc2w_t = (const float*)d_in[15];
    const float* fc2b_t = (const float*)d_in[16];
    float* out = (float*)d_out;
    (void)in_sizes; (void)n_in; (void)out_size; (void)ws_size;

    char* ws = (char*)d_ws;
    auto alloc = [&](size_t bytes) { char* p = ws; ws += (bytes + 255) & ~(size_t)255; return p; };

    bf16*  aggF1   = (bf16*)alloc((size_t)BB * 18 * 4096);
    bf16*  aggF2   = (bf16*)alloc((size_t)BB * 18 * 4096);
    bf16*  aggF3   = (bf16*)alloc((size_t)BB * 18 * 4096);
    bf16*  aggFt   = (bf16*)alloc((size_t)BB * 54 * 4096);
    float* pooledx = (float*)alloc(BB * 64 * 4);
    float* pooledc = (float*)alloc(BB * 192 * 4);
    float* att1    = (float*)alloc(BB * 4 * 4);
    float* att2    = (float*)alloc(BB * 4 * 4);
    float* att3    = (float*)alloc(BB * 4 * 4);
    float* attt    = (float*)alloc(BB * 4 * 4);
    alloc(4096);                                             // guard (stage may underrun)
    const size_t XT_BYTES  = (size_t)BB * XH * XW * 64 * 2;
    bf16* xT   = (bf16*)alloc(XT_BYTES);
    alloc(4096);                                             // guard
    const size_t CAT_BYTES = (size_t)BB * CHH * CWD * CATC * 2;
    bf16* catT = (bf16*)alloc(CAT_BYTES);
    alloc(4096);                                             // guard

    hipMemsetAsync(pooledx, 0, BB * 64 * 4, stream);
    hipMemsetAsync(pooledc, 0, BB * 192 * 4, stream);

    // border-only zeroing (interiors are fully overwritten every call)
    {
        int slots_x = 2 * XPAD * XW + (XH - 2 * XPAD) * 2 * XPAD;    // 2112
        int nthr = BB * slots_x * (64 / 8);
        zero_border<<<(nthr + 255) / 256, 256, 0, stream>>>(xT, XH, XW, XPAD, 64, slots_x);
        int slots_c = 2 * CPAD * CWD + (CHH - 2 * CPAD) * 2 * CPAD;  // 516
        nthr = BB * slots_c * (CATC / 8);
        zero_border<<<(nthr + 255) / 256, 256, 0, stream>>>(catT, CHH, CWD, CPAD, CATC, slots_c);
    }

    transpose_pad_pool_x<<<dim3(128, 16), 256, 0, stream>>>(x, xT, pooledx);

    attention3<<<dim3(16, 3), 64, 0, stream>>>(pooledx,
        fc1_1, fc2w_1, fc2b_1, att1,
        fc1_2, fc2w_2, fc2b_2, att2,
        fc1_3, fc2w_3, fc2b_3, att3);

    aggw_frag<64><<<dim3(64, 16), 256, 0, stream>>>(w1, att1, aggF1);
    aggw_frag<64><<<dim3(64, 16), 256, 0, stream>>>(w2, att2, aggF2);
    aggw_frag<64><<<dim3(64, 16), 256, 0, stream>>>(w3, att3, aggF3);

    dim3 cgrid(2, 8, 16);
    conv_mfma<1, 64, false><<<cgrid, 512, 0, stream>>>(xT, XH, XW, XPAD, aggF1, nullptr, nullptr, catT, 0,   pooledc);
    conv_mfma<2, 64, false><<<cgrid, 512, 0, stream>>>(xT, XH, XW, XPAD, aggF2, nullptr, nullptr, catT, 64,  pooledc);
    conv_mfma<4, 64, false><<<cgrid, 512, 0, stream>>>(xT, XH, XW, XPAD, aggF3, nullptr, nullptr, catT, 128, pooledc);

    attention_one<<<16, 64, 0, stream>>>(pooledc, CATC, fc1_t, 49, fc2w_t, fc2b_t, attt);
    aggw_frag<192><<<dim3(64, 16), 256, 0, stream>>>(wt, attt, aggFt);

    conv_mfma<1, 192, true><<<cgrid, 512, 0, stream>>>(catT, CHH, CWD, CPAD, aggFt, x, out, nullptr, 0, nullptr);
}

// Round 7
// 272.725 us; speedup vs baseline: 1.9206x; 1.0590x over previous
//
#include <hip/hip_runtime.h>
#include <hip/hip_bf16.h>

typedef __hip_bfloat16 bf16;
typedef __attribute__((ext_vector_type(4))) float f32x4;
typedef __attribute__((ext_vector_type(8))) short bf16x8;
typedef __attribute__((ext_vector_type(4))) short s16x4;

#define BB 16
#define HH 128
#define WW 128
#define HWSZ (HH*WW)
// xT: [16][136][136][64] bf16, pad 4
#define XH 136
#define XW 136
#define XPAD 4
// catT: [16][130][130][192] bf16, pad 1
#define CHH 130
#define CWD 130
#define CPAD 1
#define CATC 192

// ---------------- zero only the pad borders of a channel-fast tensor ----------------
__global__ void zero_border(bf16* __restrict__ base, int HP, int WP, int PAD,
                            int Cdim, int slots)
{
    int cg8 = Cdim >> 3;
    int per_b = slots * cg8;
    int idx = blockIdx.x * 256 + threadIdx.x;
    if (idx >= BB * per_b) return;
    int b = idx / per_b;
    int rem = idx - b * per_b;
    int slot = rem / cg8;
    int cg = rem - slot * cg8;
    int top = PAD * WP;
    int h, w;
    if (slot < top)            { h = slot / WP;            w = slot % WP; }
    else if (slot < 2 * top)   { int s = slot - top;       h = HP - PAD + s / WP; w = s % WP; }
    else {
        int s = slot - 2 * top;
        int row = s / (2 * PAD), t = s - row * (2 * PAD);
        h = PAD + row;
        w = (t < PAD) ? t : (WP - 2 * PAD + t);
    }
    bf16x8 z = {0,0,0,0,0,0,0,0};
    *(bf16x8*)(base + (((size_t)b * HP + h) * WP + w) * Cdim + cg * 8) = z;
}

// ---------------- LDS-tiled transpose + pad x -> bf16 channel-fast, fused pool ----------------
__global__ __launch_bounds__(256)
void transpose_pad_pool_x(const float* __restrict__ x, bf16* __restrict__ xT,
                          float* __restrict__ pooledx)
{
    __shared__ float tile[128 * 65];
    const int h = blockIdx.x, b = blockIdx.y;
    const int t = threadIdx.x;
    const int w  = t & 127;
    const int chalf = t >> 7;            // 0/1

    const float* xb = x + (((size_t)b * 64) * HH + h) * WW + w;
    #pragma unroll
    for (int it = 0; it < 32; ++it) {
        int c = it * 2 + chalf;
        tile[w * 65 + c] = xb[(size_t)c * HWSZ];
    }
    __syncthreads();

    bf16* dst = xT + (((size_t)b * XH + (h + XPAD)) * XW + XPAD) * 64;
    #pragma unroll
    for (int it = 0; it < 4; ++it) {
        int v  = t + it * 256;           // 0..1023
        int ww = v >> 3;
        int c0 = (v & 7) * 8;
        const float* src = tile + ww * 65 + c0;
        bf16x8 pk;
        #pragma unroll
        for (int j = 0; j < 8; ++j)
            pk[j] = __builtin_bit_cast(short, __float2bfloat16(src[j]));
        *(bf16x8*)(dst + (size_t)ww * 64 + c0) = pk;
    }

    if (t < 64) {
        float s = 0.f;
        #pragma unroll 4
        for (int ww = 0; ww < 128; ++ww) s += tile[ww * 65 + t];
        atomicAdd(pooledx + b * 64 + t, s);
    }
}

// ---------------- attention MLP body ----------------
__device__ __forceinline__ void attn_body(int b, const float* pooled, int Cin,
                                          const float* fc1, int hid,
                                          const float* fc2w, const float* fc2b,
                                          float* att, float* sp, float* sh, float* slg)
{
    for (int c = threadIdx.x; c < Cin; c += 64) sp[c] = pooled[b * Cin + c];
    __syncthreads();
    int j = threadIdx.x;
    if (j < hid) {
        float s = 0.f;
        const float4* f4 = (const float4*)(fc1 + (size_t)j * Cin);
        for (int c4 = 0; c4 < Cin / 4; ++c4) {
            float4 v = f4[c4];
            s += v.x * sp[c4*4+0] + v.y * sp[c4*4+1] + v.z * sp[c4*4+2] + v.w * sp[c4*4+3];
        }
        sh[j] = s > 0.f ? s * (1.0f / 16384.0f) : 0.f;   // fold 1/HW
    }
    __syncthreads();
    int k = threadIdx.x;
    if (k < 4) {
        float s = fc2b[k];
        for (int jj = 0; jj < hid; ++jj) s += fc2w[k * hid + jj] * sh[jj];
        slg[k] = s * (1.0f / 34.0f);
    }
    __syncthreads();
    if (threadIdx.x == 0) {
        float m = fmaxf(fmaxf(slg[0], slg[1]), fmaxf(slg[2], slg[3]));
        float e0 = expf(slg[0]-m), e1 = expf(slg[1]-m), e2 = expf(slg[2]-m), e3 = expf(slg[3]-m);
        float inv = 1.0f / (e0+e1+e2+e3);
        att[b*4+0] = e0*inv; att[b*4+1] = e1*inv; att[b*4+2] = e2*inv; att[b*4+3] = e3*inv;
    }
}

__global__ void attention3(const float* __restrict__ pooled,
                           const float* f1a, const float* f2a, const float* ba, float* aa,
                           const float* f1b, const float* f2b, const float* bb, float* ab,
                           const float* f1c, const float* f2c, const float* bc, float* ac)
{
    __shared__ float sp[192], sh[64], slg[4];
    int br = blockIdx.y;
    const float* fc1  = br == 0 ? f1a : br == 1 ? f1b : f1c;
    const float* fc2w = br == 0 ? f2a : br == 1 ? f2b : f2c;
    const float* fc2b = br == 0 ? ba  : br == 1 ? bb  : bc;
    float* att        = br == 0 ? aa  : br == 1 ? ab  : ac;
    attn_body(blockIdx.x, pooled, 64, fc1, 17, fc2w, fc2b, att, sp, sh, slg);
}

__global__ void attention_one(const float* __restrict__ pooled, int Cin,
                              const float* __restrict__ fc1, int hid,
                              const float* __restrict__ fc2w,
                              const float* __restrict__ fc2b, float* __restrict__ att)
{
    __shared__ float sp[192], sh[64], slg[4];
    attn_body(blockIdx.x, pooled, Cin, fc1, hid, fc2w, fc2b, att, sp, sh, slg);
}

// ---------------- aggregate weights -> bf16, MFMA A-fragment order ----------------
// out layout: [b][s = chunk*9+tap][m 4][lane 64][j 8] bf16, where
// co = m*16 + (lane&15), ci = chunk*32 + (lane>>4)*8 + j.
template<int CIN>
__global__ void aggw_frag(const float* __restrict__ w, const float* __restrict__ att,
                          bf16* __restrict__ out)
{
    constexpr int C9 = CIN * 9;
    constexpr int NS = (CIN / 32) * 9;
    __shared__ float wl[4 * C9];
    const int co = blockIdx.x, b = blockIdx.y;
    for (int i = threadIdx.x; i < 4 * C9; i += 256) {
        int k = i / C9, rem = i - k * C9;
        wl[i] = w[((size_t)k * 64 + co) * C9 + rem];
    }
    __syncthreads();
    float a0 = att[b*4+0], a1 = att[b*4+1], a2 = att[b*4+2], a3 = att[b*4+3];
    const int m = co >> 4, l15 = co & 15;
    char* ob = (char*)out + (size_t)b * NS * 4096;
    for (int t = threadIdx.x; t < NS * 32; t += 256) {
        int s = t >> 5, rem = t & 31;
        int gg = rem >> 3, j = rem & 7;
        int chunk = s / 9, tap = s - chunk * 9;
        int ci = chunk * 32 + gg * 8 + j;
        float v = a0 * wl[ci*9 + tap] + a1 * wl[C9 + ci*9 + tap]
                + a2 * wl[2*C9 + ci*9 + tap] + a3 * wl[3*C9 + ci*9 + tap];
        *(bf16*)(ob + ((size_t)((s*4 + m) * 64 + (gg*16 + l15))) * 16 + j * 2) = __float2bfloat16(v);
    }
}

// ---------------- MFMA implicit-GEMM dynamic conv, simple 2-barrier loop ----------------
// grid (2 wt, 16 hb, 16 b) = 512 blocks (2/CU), 512 threads (8 waves).
// Block: 64 co x 8 out rows (dil-strided) x 64 w. Wave = 1 row, 4 n-tiles x 4 m-tiles.
// LDS: [A 36 KB][X 10 rows x (64+2*DIL) slots x 64 B][sco], single-buffered.
template<int DIL, int CIN, bool RESID>
__global__ __launch_bounds__(512, 4)
void conv_mfma(const bf16* __restrict__ inT, int HPd, int WPd, int PAD,
               const bf16* __restrict__ aggwF,
               const float* __restrict__ xres, float* __restrict__ outf,
               bf16* __restrict__ catT, int catbase, float* __restrict__ poolc)
{
    constexpr int NCHUNK = CIN / 32;
    constexpr int SLOTS  = 64 + 2 * DIL;
    constexpr int ROWB   = SLOTS * 64;            // bytes per staged row
    constexpr int XBYTES = 10 * ROWB;
    constexpr int XSEG   = (XBYTES + 1023) / 1024;
    constexpr int ABYTES = 36864;                  // 9 taps x 4 m x 1024
    constexpr int ASEG   = 36;
    constexpr int TOTSEG = XSEG + ASEG;
    constexpr int MAXT   = (TOTSEG + 7) / 8;
    constexpr int XBASE  = ABYTES;
    constexpr int SCOO   = ABYTES + XSEG * 1024;
    __shared__ __align__(1024) char lds[SCOO + 256];
    float* sco = (float*)(lds + SCOO);

    const int b  = blockIdx.z;
    const int hb = blockIdx.y;               // 0..15
    const int wt = blockIdx.x;               // 0..1
    const int r  = hb % DIL;
    const int q  = hb / DIL;

    const int tid  = threadIdx.x;
    const int wv   = tid >> 6;               // wave = output row
    const int lane = tid & 63;
    const int n16  = lane & 15;
    const int g    = lane >> 4;

    const char* inB = (const char*)inT;
    const char* awB = (const char*)aggwF + (size_t)b * (NCHUNK * ABYTES);

    if (!RESID && tid < 64) sco[tid] = 0.f;

    // per-lane X staging source offsets for chunk 0 (advance by +64 per chunk)
    int xoff[6];
    #pragma unroll
    for (int t = 0; t < 6; ++t) {
        int i = wv + 8 * t;
        xoff[t] = 0;
        if (i < XSEG) {
            int o = i * 1024 + lane * 16;
            if (o < XBYTES) {
                int row   = o / ROWB;
                int rem   = o - row * ROWB;
                int wslot = rem >> 6;
                int ci2   = rem & 63;
                int h_in  = (q * 8 + row - 1) * DIL + r;
                xoff[t] = ((b * HPd + PAD + h_in) * WPd + (PAD + wt * 64 - DIL + wslot)) * (CIN * 2) + ci2;
            }
        }
    }

    auto stage = [&](int c) {
        #pragma unroll
        for (int t = 0; t < MAXT; ++t) {
            int i = wv + 8 * t;
            if (i >= TOTSEG) break;
            if (i < XSEG) {
                __builtin_amdgcn_global_load_lds(
                    (const __attribute__((address_space(1))) void*)(inB + (size_t)(xoff[t] + c * 64)),
                    (__attribute__((address_space(3))) void*)(lds + XBASE + i * 1024),
                    16, 0, 0);
            } else {
                __builtin_amdgcn_global_load_lds(
                    (const __attribute__((address_space(1))) void*)(awB + (size_t)c * ABYTES + (i - XSEG) * 1024 + lane * 16),
                    (__attribute__((address_space(3))) void*)(lds + (i - XSEG) * 1024),
                    16, 0, 0);
            }
        }
    };

    f32x4 acc[4][4];
    #pragma unroll
    for (int nt = 0; nt < 4; ++nt)
        #pragma unroll
        for (int m = 0; m < 4; ++m) { f32x4 z = {0.f,0.f,0.f,0.f}; acc[nt][m] = z; }

    for (int c = 0; c < NCHUNK; ++c) {
        stage(c);
        __syncthreads();                     // drains vmcnt + barrier
        #pragma unroll
        for (int tap = 0; tap < 9; ++tap) {
            const int kh = tap / 3, kw = tap - kh * 3;
            bf16x8 a[4];
            #pragma unroll
            for (int m = 0; m < 4; ++m)
                a[m] = *(const bf16x8*)(lds + tap * 4096 + m * 1024 + lane * 16);
            #pragma unroll
            for (int nt = 0; nt < 4; ++nt) {
                const bf16x8 bfr = *(const bf16x8*)(lds + XBASE + (wv + kh) * ROWB
                                                    + (nt * 16 + n16 + kw * DIL) * 64 + g * 16);
                #pragma unroll
                for (int m = 0; m < 4; ++m)
                    acc[nt][m] = __builtin_amdgcn_mfma_f32_16x16x32_bf16(a[m], bfr, acc[nt][m], 0, 0, 0);
            }
        }
        __syncthreads();                     // protect buffer before next stage
    }

    // ---- epilogue ----
    const int h_out = (q * 8 + wv) * DIL + r;
    if (RESID) {
        #pragma unroll
        for (int nt = 0; nt < 4; ++nt) {
            int w_out = wt * 64 + nt * 16 + n16;
            #pragma unroll
            for (int m = 0; m < 4; ++m) {
                int co = m * 16 + g * 4;
                size_t base = (((size_t)b * 64 + co) * HH + h_out) * WW + w_out;
                #pragma unroll
                for (int qq = 0; qq < 4; ++qq) {
                    size_t idx = base + (size_t)qq * HWSZ;
                    outf[idx] = xres[idx] + acc[nt][m][qq];
                }
            }
        }
    } else {
        float csum[4][4];
        #pragma unroll
        for (int m = 0; m < 4; ++m)
            #pragma unroll
            for (int qq = 0; qq < 4; ++qq) csum[m][qq] = 0.f;
        #pragma unroll
        for (int nt = 0; nt < 4; ++nt) {
            int w_out = wt * 64 + nt * 16 + n16;
            bf16* dst = catT + (((size_t)b * CHH + (CPAD + h_out)) * CWD + (CPAD + w_out)) * CATC + catbase;
            #pragma unroll
            for (int m = 0; m < 4; ++m) {
                s16x4 pk;
                #pragma unroll
                for (int qq = 0; qq < 4; ++qq) {
                    float v = acc[nt][m][qq];
                    v = v >= 0.f ? v : 0.1f * v;        // leaky
                    csum[m][qq] += v;
                    pk[qq] = __builtin_bit_cast(short, __float2bfloat16(v));
                }
                *(s16x4*)((char*)dst + (m * 16 + g * 4) * 2) = pk;
            }
        }
        #pragma unroll
        for (int m = 0; m < 4; ++m)
            #pragma unroll
            for (int qq = 0; qq < 4; ++qq) {
                float v = csum[m][qq];
                v += __shfl_xor(v, 1, 64);
                v += __shfl_xor(v, 2, 64);
                v += __shfl_xor(v, 4, 64);
                v += __shfl_xor(v, 8, 64);
                if (n16 == 0) atomicAdd(&sco[m * 16 + g * 4 + qq], v);
            }
        __syncthreads();
        if (tid < 64) atomicAdd(poolc + b * CATC + catbase + tid, sco[tid]);
    }
}

// ---------------- launch ----------------
extern "C" void kernel_launch(void* const* d_in, const int* in_sizes, int n_in,
                              void* d_out, int out_size, void* d_ws, size_t ws_size,
                              hipStream_t stream) {
    const float* x      = (const float*)d_in[0];
    const float* w1     = (const float*)d_in[1];
    const float* fc1_1  = (const float*)d_in[2];
    const float* fc2w_1 = (const float*)d_in[3];
    const float* fc2b_1 = (const float*)d_in[4];
    const float* w2     = (const float*)d_in[5];
    const float* fc1_2  = (const float*)d_in[6];
    const float* fc2w_2 = (const float*)d_in[7];
    const float* fc2b_2 = (const float*)d_in[8];
    const float* w3     = (const float*)d_in[9];
    const float* fc1_3  = (const float*)d_in[10];
    const float* fc2w_3 = (const float*)d_in[11];
    const float* fc2b_3 = (const float*)d_in[12];
    const float* wt     = (const float*)d_in[13];
    const float* fc1_t  = (const float*)d_in[14];
    const float* fc2w_t = (const float*)d_in[15];
    const float* fc2b_t = (const float*)d_in[16];
    float* out = (float*)d_out;
    (void)in_sizes; (void)n_in; (void)out_size; (void)ws_size;

    char* ws = (char*)d_ws;
    auto alloc = [&](size_t bytes) { char* p = ws; ws += (bytes + 255) & ~(size_t)255; return p; };

    bf16*  aggF1   = (bf16*)alloc((size_t)BB * 18 * 4096);
    bf16*  aggF2   = (bf16*)alloc((size_t)BB * 18 * 4096);
    bf16*  aggF3   = (bf16*)alloc((size_t)BB * 18 * 4096);
    bf16*  aggFt   = (bf16*)alloc((size_t)BB * 54 * 4096);
    float* pooledx = (float*)alloc(BB * 64 * 4);
    float* pooledc = (float*)alloc(BB * 192 * 4);
    float* att1    = (float*)alloc(BB * 4 * 4);
    float* att2    = (float*)alloc(BB * 4 * 4);
    float* att3    = (float*)alloc(BB * 4 * 4);
    float* attt    = (float*)alloc(BB * 4 * 4);
    alloc(65536);                                            // guard
    const size_t XT_BYTES  = (size_t)BB * XH * XW * 64 * 2;
    bf16* xT   = (bf16*)alloc(XT_BYTES);
    alloc(65536);                                            // guard
    const size_t CAT_BYTES = (size_t)BB * CHH * CWD * CATC * 2;
    bf16* catT = (bf16*)alloc(CAT_BYTES);
    alloc(65536);                                            // guard

    hipMemsetAsync(pooledx, 0, BB * 64 * 4, stream);
    hipMemsetAsync(pooledc, 0, BB * 192 * 4, stream);

    // border-only zeroing (interiors are fully overwritten every call)
    {
        int slots_x = 2 * XPAD * XW + (XH - 2 * XPAD) * 2 * XPAD;    // 2112
        int nthr = BB * slots_x * (64 / 8);
        zero_border<<<(nthr + 255) / 256, 256, 0, stream>>>(xT, XH, XW, XPAD, 64, slots_x);
        int slots_c = 2 * CPAD * CWD + (CHH - 2 * CPAD) * 2 * CPAD;  // 516
        nthr = BB * slots_c * (CATC / 8);
        zero_border<<<(nthr + 255) / 256, 256, 0, stream>>>(catT, CHH, CWD, CPAD, CATC, slots_c);
    }

    transpose_pad_pool_x<<<dim3(128, 16), 256, 0, stream>>>(x, xT, pooledx);

    attention3<<<dim3(16, 3), 64, 0, stream>>>(pooledx,
        fc1_1, fc2w_1, fc2b_1, att1,
        fc1_2, fc2w_2, fc2b_2, att2,
        fc1_3, fc2w_3, fc2b_3, att3);

    aggw_frag<64><<<dim3(64, 16), 256, 0, stream>>>(w1, att1, aggF1);
    aggw_frag<64><<<dim3(64, 16), 256, 0, stream>>>(w2, att2, aggF2);
    aggw_frag<64><<<dim3(64, 16), 256, 0, stream>>>(w3, att3, aggF3);

    dim3 cgrid(2, 16, 16);
    conv_mfma<1, 64, false><<<cgrid, 512, 0, stream>>>(xT, XH, XW, XPAD, aggF1, nullptr, nullptr, catT, 0,   pooledc);
    conv_mfma<2, 64, false><<<cgrid, 512, 0, stream>>>(xT, XH, XW, XPAD, aggF2, nullptr, nullptr, catT, 64,  pooledc);
    conv_mfma<4, 64, false><<<cgrid, 512, 0, stream>>>(xT, XH, XW, XPAD, aggF3, nullptr, nullptr, catT, 128, pooledc);

    attention_one<<<16, 64, 0, stream>>>(pooledc, CATC, fc1_t, 49, fc2w_t, fc2b_t, attt);
    aggw_frag<192><<<dim3(64, 16), 256, 0, stream>>>(wt, attt, aggFt);

    conv_mfma<1, 192, true><<<cgrid, 512, 0, stream>>>(catT, CHH, CWD, CPAD, aggFt, x, out, nullptr, 0, nullptr);
}

// Round 8
// 271.696 us; speedup vs baseline: 1.9278x; 1.0038x over previous
//
#include <hip/hip_runtime.h>
#include <hip/hip_bf16.h>

typedef __hip_bfloat16 bf16;
typedef __attribute__((ext_vector_type(4))) float f32x4;
typedef __attribute__((ext_vector_type(8))) short bf16x8;
typedef __attribute__((ext_vector_type(4))) short s16x4;

#define BB 16
#define HH 128
#define WW 128
#define HWSZ (HH*WW)
// xT: [16][136][136][64] bf16, pad 4
#define XH 136
#define XW 136
#define XPAD 4
// catT: [16][130][130][192] bf16, pad 1
#define CHH 130
#define CWD 130
#define CPAD 1
#define CATC 192

// ---------------- zero only the pad borders of a channel-fast tensor ----------------
__global__ void zero_border(bf16* __restrict__ base, int HP, int WP, int PAD,
                            int Cdim, int slots)
{
    int cg8 = Cdim >> 3;
    int per_b = slots * cg8;
    int idx = blockIdx.x * 256 + threadIdx.x;
    if (idx >= BB * per_b) return;
    int b = idx / per_b;
    int rem = idx - b * per_b;
    int slot = rem / cg8;
    int cg = rem - slot * cg8;
    int top = PAD * WP;
    int h, w;
    if (slot < top)            { h = slot / WP;            w = slot % WP; }
    else if (slot < 2 * top)   { int s = slot - top;       h = HP - PAD + s / WP; w = s % WP; }
    else {
        int s = slot - 2 * top;
        int row = s / (2 * PAD), t = s - row * (2 * PAD);
        h = PAD + row;
        w = (t < PAD) ? t : (WP - 2 * PAD + t);
    }
    bf16x8 z = {0,0,0,0,0,0,0,0};
    *(bf16x8*)(base + (((size_t)b * HP + h) * WP + w) * Cdim + cg * 8) = z;
}

// ---------------- LDS-tiled transpose + pad x -> bf16 channel-fast, fused pool ----------------
__global__ __launch_bounds__(256)
void transpose_pad_pool_x(const float* __restrict__ x, bf16* __restrict__ xT,
                          float* __restrict__ pooledx)
{
    __shared__ float tile[128 * 65];
    const int h = blockIdx.x, b = blockIdx.y;
    const int t = threadIdx.x;
    const int w  = t & 127;
    const int chalf = t >> 7;            // 0/1

    const float* xb = x + (((size_t)b * 64) * HH + h) * WW + w;
    #pragma unroll
    for (int it = 0; it < 32; ++it) {
        int c = it * 2 + chalf;
        tile[w * 65 + c] = xb[(size_t)c * HWSZ];
    }
    __syncthreads();

    bf16* dst = xT + (((size_t)b * XH + (h + XPAD)) * XW + XPAD) * 64;
    #pragma unroll
    for (int it = 0; it < 4; ++it) {
        int v  = t + it * 256;           // 0..1023
        int ww = v >> 3;
        int c0 = (v & 7) * 8;
        const float* src = tile + ww * 65 + c0;
        bf16x8 pk;
        #pragma unroll
        for (int j = 0; j < 8; ++j)
            pk[j] = __builtin_bit_cast(short, __float2bfloat16(src[j]));
        *(bf16x8*)(dst + (size_t)ww * 64 + c0) = pk;
    }

    if (t < 64) {
        float s = 0.f;
        #pragma unroll 4
        for (int ww = 0; ww < 128; ++ww) s += tile[ww * 65 + t];
        atomicAdd(pooledx + b * 64 + t, s);
    }
}

// ---------------- attention MLP body ----------------
__device__ __forceinline__ void attn_body(int b, const float* pooled, int Cin,
                                          const float* fc1, int hid,
                                          const float* fc2w, const float* fc2b,
                                          float* att, float* sp, float* sh, float* slg)
{
    for (int c = threadIdx.x; c < Cin; c += 64) sp[c] = pooled[b * Cin + c];
    __syncthreads();
    int j = threadIdx.x;
    if (j < hid) {
        float s = 0.f;
        const float4* f4 = (const float4*)(fc1 + (size_t)j * Cin);
        for (int c4 = 0; c4 < Cin / 4; ++c4) {
            float4 v = f4[c4];
            s += v.x * sp[c4*4+0] + v.y * sp[c4*4+1] + v.z * sp[c4*4+2] + v.w * sp[c4*4+3];
        }
        sh[j] = s > 0.f ? s * (1.0f / 16384.0f) : 0.f;   // fold 1/HW
    }
    __syncthreads();
    int k = threadIdx.x;
    if (k < 4) {
        float s = fc2b[k];
        for (int jj = 0; jj < hid; ++jj) s += fc2w[k * hid + jj] * sh[jj];
        slg[k] = s * (1.0f / 34.0f);
    }
    __syncthreads();
    if (threadIdx.x == 0) {
        float m = fmaxf(fmaxf(slg[0], slg[1]), fmaxf(slg[2], slg[3]));
        float e0 = expf(slg[0]-m), e1 = expf(slg[1]-m), e2 = expf(slg[2]-m), e3 = expf(slg[3]-m);
        float inv = 1.0f / (e0+e1+e2+e3);
        att[b*4+0] = e0*inv; att[b*4+1] = e1*inv; att[b*4+2] = e2*inv; att[b*4+3] = e3*inv;
    }
}

__global__ void attention3(const float* __restrict__ pooled,
                           const float* f1a, const float* f2a, const float* ba, float* aa,
                           const float* f1b, const float* f2b, const float* bb, float* ab,
                           const float* f1c, const float* f2c, const float* bc, float* ac)
{
    __shared__ float sp[192], sh[64], slg[4];
    int br = blockIdx.y;
    const float* fc1  = br == 0 ? f1a : br == 1 ? f1b : f1c;
    const float* fc2w = br == 0 ? f2a : br == 1 ? f2b : f2c;
    const float* fc2b = br == 0 ? ba  : br == 1 ? bb  : bc;
    float* att        = br == 0 ? aa  : br == 1 ? ab  : ac;
    attn_body(blockIdx.x, pooled, 64, fc1, 17, fc2w, fc2b, att, sp, sh, slg);
}

__global__ void attention_one(const float* __restrict__ pooled, int Cin,
                              const float* __restrict__ fc1, int hid,
                              const float* __restrict__ fc2w,
                              const float* __restrict__ fc2b, float* __restrict__ att)
{
    __shared__ float sp[192], sh[64], slg[4];
    attn_body(blockIdx.x, pooled, Cin, fc1, hid, fc2w, fc2b, att, sp, sh, slg);
}

// ---------------- aggregate weights -> bf16, MFMA A-fragment order ----------------
// out layout: [b][s = chunk*9+tap][m 4][lane 64][j 8] bf16, where
// co = m*16 + (lane&15), ci = chunk*32 + (lane>>4)*8 + j.
template<int CIN>
__global__ void aggw_frag(const float* __restrict__ w, const float* __restrict__ att,
                          bf16* __restrict__ out)
{
    constexpr int C9 = CIN * 9;
    constexpr int NS = (CIN / 32) * 9;
    __shared__ float wl[4 * C9];
    const int co = blockIdx.x, b = blockIdx.y;
    for (int i = threadIdx.x; i < 4 * C9; i += 256) {
        int k = i / C9, rem = i - k * C9;
        wl[i] = w[((size_t)k * 64 + co) * C9 + rem];
    }
    __syncthreads();
    float a0 = att[b*4+0], a1 = att[b*4+1], a2 = att[b*4+2], a3 = att[b*4+3];
    const int m = co >> 4, l15 = co & 15;
    char* ob = (char*)out + (size_t)b * NS * 4096;
    for (int t = threadIdx.x; t < NS * 32; t += 256) {
        int s = t >> 5, rem = t & 31;
        int gg = rem >> 3, j = rem & 7;
        int chunk = s / 9, tap = s - chunk * 9;
        int ci = chunk * 32 + gg * 8 + j;
        float v = a0 * wl[ci*9 + tap] + a1 * wl[C9 + ci*9 + tap]
                + a2 * wl[2*C9 + ci*9 + tap] + a3 * wl[3*C9 + ci*9 + tap];
        *(bf16*)(ob + ((size_t)((s*4 + m) * 64 + (gg*16 + l15))) * 16 + j * 2) = __float2bfloat16(v);
    }
}

// ---------------- MFMA implicit-GEMM conv core ----------------
// 512 threads = 8 waves; block = 64 co x 8 dil-strided rows x 64 w; wave = 1 row.
// X LDS layout (conflict-free, g-major): [row 10][g 4][slot SLOTS][16B].
// ALDS: A staged in LDS [tap][m][lane][16B]; else A read per-lane from global (L2).
template<int DIL, int CIN, bool RESID, bool ALDS>
__device__ __forceinline__ void conv_core(
    int b, int hb, int wt,
    const bf16* __restrict__ inT, int HPd, int WPd, int PAD,
    const bf16* __restrict__ aggwF,
    const float* __restrict__ xres, float* __restrict__ outf,
    bf16* __restrict__ catT, int catbase, float* __restrict__ poolc,
    char* lds, float* sco)
{
    constexpr int NCHUNK = CIN / 32;
    constexpr int SLOTS  = 64 + 2 * DIL;
    constexpr int ROWB   = SLOTS * 64;
    constexpr int XBYTES = 10 * ROWB;
    constexpr int XSEG   = (XBYTES + 1023) / 1024;
    constexpr int ABYTES = 36864;
    constexpr int ASEG   = ALDS ? 36 : 0;
    constexpr int XBASE  = ALDS ? ABYTES : 0;
    constexpr int TOTSEG = XSEG + ASEG;
    constexpr int MAXT   = (TOTSEG + 7) / 8;

    const int r  = hb % DIL;
    const int q  = hb / DIL;
    const int tid  = threadIdx.x;
    const int wv   = tid >> 6;
    const int lane = tid & 63;
    const int n16  = lane & 15;
    const int g    = lane >> 4;

    const char* inB = (const char*)inT;
    const char* awB = (const char*)aggwF + (size_t)b * (NCHUNK * ABYTES);

    if (!RESID && tid < 64) sco[tid] = 0.f;

    // precomputed conflict-free B-read bases (kh folds into compile-time imm)
    int baddr[12];
    #pragma unroll
    for (int nt = 0; nt < 4; ++nt)
        #pragma unroll
        for (int kw = 0; kw < 3; ++kw)
            baddr[nt*3+kw] = XBASE + wv * ROWB + g * (SLOTS * 16)
                             + (nt * 16 + n16 + kw * DIL) * 16;

    // per-lane X staging source offsets for chunk 0 (advance +64 B per chunk)
    int xoff[MAXT];
    #pragma unroll
    for (int t = 0; t < MAXT; ++t) {
        int i = wv + 8 * t;
        xoff[t] = 0;
        if (i < XSEG) {
            int o = i * 1024 + lane * 16;
            if (o < XBYTES) {
                int row  = o / ROWB;
                int rem  = o - row * ROWB;
                int g2   = rem / (SLOTS * 16);
                int slot = (rem - g2 * (SLOTS * 16)) >> 4;
                int h_in = (q * 8 + row - 1) * DIL + r;
                xoff[t] = ((b * HPd + PAD + h_in) * WPd + (PAD + wt * 64 - DIL + slot)) * (CIN * 2)
                          + g2 * 16;
            }
        }
    }

    auto stage = [&](int c) {
        #pragma unroll
        for (int t = 0; t < MAXT; ++t) {
            int i = wv + 8 * t;
            if (i >= TOTSEG) break;
            if (i < XSEG) {
                __builtin_amdgcn_global_load_lds(
                    (const __attribute__((address_space(1))) void*)(inB + (size_t)(xoff[t] + c * 64)),
                    (__attribute__((address_space(3))) void*)(lds + XBASE + i * 1024), 16, 0, 0);
            } else if (ALDS) {
                __builtin_amdgcn_global_load_lds(
                    (const __attribute__((address_space(1))) void*)(awB + (size_t)c * ABYTES + (i - XSEG) * 1024 + lane * 16),
                    (__attribute__((address_space(3))) void*)(lds + (i - XSEG) * 1024), 16, 0, 0);
            }
        }
    };

    f32x4 acc[4][4];
    #pragma unroll
    for (int nt = 0; nt < 4; ++nt)
        #pragma unroll
        for (int m = 0; m < 4; ++m) { f32x4 z = {0.f,0.f,0.f,0.f}; acc[nt][m] = z; }

    for (int c = 0; c < NCHUNK; ++c) {
        stage(c);
        __syncthreads();
        const char* awC = awB + (size_t)c * ABYTES + (size_t)lane * 16;
        if (ALDS) {
            #pragma unroll
            for (int tap = 0; tap < 9; ++tap) {
                const int kh = tap / 3, kw = tap - kh * 3;
                bf16x8 a[4];
                #pragma unroll
                for (int m = 0; m < 4; ++m)
                    a[m] = *(const bf16x8*)(lds + (tap * 4 + m) * 1024 + lane * 16);
                #pragma unroll
                for (int nt = 0; nt < 4; ++nt) {
                    const bf16x8 bfr = *(const bf16x8*)(lds + baddr[nt * 3 + kw] + kh * ROWB);
                    #pragma unroll
                    for (int m = 0; m < 4; ++m)
                        acc[nt][m] = __builtin_amdgcn_mfma_f32_16x16x32_bf16(a[m], bfr, acc[nt][m], 0, 0, 0);
                }
            }
        } else {
            #pragma unroll 3
            for (int tap = 0; tap < 9; ++tap) {
                const int kh = tap / 3, kw = tap - kh * 3;
                bf16x8 a[4];
                #pragma unroll
                for (int m = 0; m < 4; ++m)
                    a[m] = *(const bf16x8*)(awC + (size_t)((tap * 4 + m) * 1024));
                #pragma unroll
                for (int nt = 0; nt < 4; ++nt) {
                    const bf16x8 bfr = *(const bf16x8*)(lds + baddr[nt * 3 + kw] + kh * ROWB);
                    #pragma unroll
                    for (int m = 0; m < 4; ++m)
                        acc[nt][m] = __builtin_amdgcn_mfma_f32_16x16x32_bf16(a[m], bfr, acc[nt][m], 0, 0, 0);
                }
            }
        }
        __syncthreads();
    }

    // ---- epilogue ----
    const int h_out = (q * 8 + wv) * DIL + r;
    if (RESID) {
        #pragma unroll
        for (int nt = 0; nt < 4; ++nt) {
            int w_out = wt * 64 + nt * 16 + n16;
            #pragma unroll
            for (int m = 0; m < 4; ++m) {
                int co = m * 16 + g * 4;
                size_t base = (((size_t)b * 64 + co) * HH + h_out) * WW + w_out;
                #pragma unroll
                for (int qq = 0; qq < 4; ++qq) {
                    size_t idx = base + (size_t)qq * HWSZ;
                    outf[idx] = xres[idx] + acc[nt][m][qq];
                }
            }
        }
    } else {
        float csum[4][4];
        #pragma unroll
        for (int m = 0; m < 4; ++m)
            #pragma unroll
            for (int qq = 0; qq < 4; ++qq) csum[m][qq] = 0.f;
        #pragma unroll
        for (int nt = 0; nt < 4; ++nt) {
            int w_out = wt * 64 + nt * 16 + n16;
            bf16* dst = catT + (((size_t)b * CHH + (CPAD + h_out)) * CWD + (CPAD + w_out)) * CATC + catbase;
            #pragma unroll
            for (int m = 0; m < 4; ++m) {
                s16x4 pk;
                #pragma unroll
                for (int qq = 0; qq < 4; ++qq) {
                    float v = acc[nt][m][qq];
                    v = v >= 0.f ? v : 0.1f * v;        // leaky
                    csum[m][qq] += v;
                    pk[qq] = __builtin_bit_cast(short, __float2bfloat16(v));
                }
                *(s16x4*)((char*)dst + (m * 16 + g * 4) * 2) = pk;
            }
        }
        #pragma unroll
        for (int m = 0; m < 4; ++m)
            #pragma unroll
            for (int qq = 0; qq < 4; ++qq) {
                float v = csum[m][qq];
                v += __shfl_xor(v, 1, 64);
                v += __shfl_xor(v, 2, 64);
                v += __shfl_xor(v, 4, 64);
                v += __shfl_xor(v, 8, 64);
                if (n16 == 0) atomicAdd(&sco[m * 16 + g * 4 + qq], v);
            }
        __syncthreads();
        if (tid < 64) atomicAdd(poolc + b * CATC + catbase + tid, sco[tid]);
    }
}

// merged 3-branch dispatch: grid (2, 16, 48); A from global (L2-resident)
__global__ __launch_bounds__(512, 4)
void conv_branch3(const bf16* __restrict__ xT,
                  const bf16* __restrict__ aggF1, const bf16* __restrict__ aggF2,
                  const bf16* __restrict__ aggF3,
                  bf16* __restrict__ catT, float* __restrict__ poolc)
{
    constexpr int SCOO = 46080;                  // max X region (DIL4: 45 segs)
    __shared__ __align__(1024) char lds[SCOO + 256];
    float* sco = (float*)(lds + SCOO);
    const int br = blockIdx.z >> 4;
    const int b  = blockIdx.z & 15;
    if (br == 0)
        conv_core<1, 64, false, false>(b, blockIdx.y, blockIdx.x, xT, XH, XW, XPAD,
                                       aggF1, nullptr, nullptr, catT, 0, poolc, lds, sco);
    else if (br == 1)
        conv_core<2, 64, false, false>(b, blockIdx.y, blockIdx.x, xT, XH, XW, XPAD,
                                       aggF2, nullptr, nullptr, catT, 64, poolc, lds, sco);
    else
        conv_core<4, 64, false, false>(b, blockIdx.y, blockIdx.x, xT, XH, XW, XPAD,
                                       aggF3, nullptr, nullptr, catT, 128, poolc, lds, sco);
}

// final conv + residual: grid (2, 16, 16); A staged in LDS
__global__ __launch_bounds__(512, 4)
void conv_final(const bf16* __restrict__ catT, const bf16* __restrict__ aggFt,
                const float* __restrict__ x, float* __restrict__ out)
{
    constexpr int XSEGF = (10 * 66 * 64 + 1023) / 1024;   // 42
    constexpr int SCOO  = 36864 + XSEGF * 1024;           // 79872
    __shared__ __align__(1024) char lds[SCOO + 256];
    conv_core<1, 192, true, true>(blockIdx.z, blockIdx.y, blockIdx.x, catT, CHH, CWD, CPAD,
                                  aggFt, x, out, nullptr, 0, nullptr, lds, (float*)(lds + SCOO));
}

// ---------------- launch ----------------
extern "C" void kernel_launch(void* const* d_in, const int* in_sizes, int n_in,
                              void* d_out, int out_size, void* d_ws, size_t ws_size,
                              hipStream_t stream) {
    const float* x      = (const float*)d_in[0];
    const float* w1     = (const float*)d_in[1];
    const float* fc1_1  = (const float*)d_in[2];
    const float* fc2w_1 = (const float*)d_in[3];
    const float* fc2b_1 = (const float*)d_in[4];
    const float* w2     = (const float*)d_in[5];
    const float* fc1_2  = (const float*)d_in[6];
    const float* fc2w_2 = (const float*)d_in[7];
    const float* fc2b_2 = (const float*)d_in[8];
    const float* w3     = (const float*)d_in[9];
    const float* fc1_3  = (const float*)d_in[10];
    const float* fc2w_3 = (const float*)d_in[11];
    const float* fc2b_3 = (const float*)d_in[12];
    const float* wt     = (const float*)d_in[13];
    const float* fc1_t  = (const float*)d_in[14];
    const float* fc2w_t = (const float*)d_in[15];
    const float* fc2b_t = (const float*)d_in[16];
    float* out = (float*)d_out;
    (void)in_sizes; (void)n_in; (void)out_size; (void)ws_size;

    char* ws = (char*)d_ws;
    auto alloc = [&](size_t bytes) { char* p = ws; ws += (bytes + 255) & ~(size_t)255; return p; };

    bf16*  aggF1   = (bf16*)alloc((size_t)BB * 18 * 4096);
    bf16*  aggF2   = (bf16*)alloc((size_t)BB * 18 * 4096);
    bf16*  aggF3   = (bf16*)alloc((size_t)BB * 18 * 4096);
    bf16*  aggFt   = (bf16*)alloc((size_t)BB * 54 * 4096);
    float* pooledx = (float*)alloc(BB * 64 * 4);
    float* pooledc = (float*)alloc(BB * 192 * 4);
    float* att1    = (float*)alloc(BB * 4 * 4);
    float* att2    = (float*)alloc(BB * 4 * 4);
    float* att3    = (float*)alloc(BB * 4 * 4);
    float* attt    = (float*)alloc(BB * 4 * 4);
    alloc(65536);                                            // guard
    const size_t XT_BYTES  = (size_t)BB * XH * XW * 64 * 2;
    bf16* xT   = (bf16*)alloc(XT_BYTES);
    alloc(65536);                                            // guard
    const size_t CAT_BYTES = (size_t)BB * CHH * CWD * CATC * 2;
    bf16* catT = (bf16*)alloc(CAT_BYTES);
    alloc(65536);                                            // guard

    hipMemsetAsync(pooledx, 0, BB * 64 * 4, stream);
    hipMemsetAsync(pooledc, 0, BB * 192 * 4, stream);

    // border-only zeroing (interiors are fully overwritten every call)
    {
        int slots_x = 2 * XPAD * XW + (XH - 2 * XPAD) * 2 * XPAD;    // 2112
        int nthr = BB * slots_x * (64 / 8);
        zero_border<<<(nthr + 255) / 256, 256, 0, stream>>>(xT, XH, XW, XPAD, 64, slots_x);
        int slots_c = 2 * CPAD * CWD + (CHH - 2 * CPAD) * 2 * CPAD;  // 516
        nthr = BB * slots_c * (CATC / 8);
        zero_border<<<(nthr + 255) / 256, 256, 0, stream>>>(catT, CHH, CWD, CPAD, CATC, slots_c);
    }

    transpose_pad_pool_x<<<dim3(128, 16), 256, 0, stream>>>(x, xT, pooledx);

    attention3<<<dim3(16, 3), 64, 0, stream>>>(pooledx,
        fc1_1, fc2w_1, fc2b_1, att1,
        fc1_2, fc2w_2, fc2b_2, att2,
        fc1_3, fc2w_3, fc2b_3, att3);

    aggw_frag<64><<<dim3(64, 16), 256, 0, stream>>>(w1, att1, aggF1);
    aggw_frag<64><<<dim3(64, 16), 256, 0, stream>>>(w2, att2, aggF2);
    aggw_frag<64><<<dim3(64, 16), 256, 0, stream>>>(w3, att3, aggF3);

    conv_branch3<<<dim3(2, 16, 48), 512, 0, stream>>>(xT, aggF1, aggF2, aggF3, catT, pooledc);

    attention_one<<<16, 64, 0, stream>>>(pooledc, CATC, fc1_t, 49, fc2w_t, fc2b_t, attt);
    aggw_frag<192><<<dim3(64, 16), 256, 0, stream>>>(wt, attt, aggFt);

    conv_final<<<dim3(2, 16, 16), 512, 0, stream>>>(catT, aggFt, x, out);
}